// Round 1
// baseline (5586.336 us; speedup 1.0000x reference)
//
#include <hip/hip_runtime.h>
#include <math.h>

#define NEG_SLOPE 0.01f

__device__ __forceinline__ float lrelu(float v) { return v > 0.0f ? v : NEG_SLOPE * v; }

// ---------------------------------------------------------------------------
// Kernel A: fused per-point MLP (3->64->64->128->1024) + masked max partial
// pool. 1 thread = 1 point; h1/h2/h3 in registers (fully unrolled, static
// indexing); weights via wave-uniform indices -> scalar loads. Output:
// partials[block][1024] = max over the block's 256 points of dot(h3, W4[:,o])
// (bias/activation deferred to the reduce kernel; lrelu is monotone).
// ---------------------------------------------------------------------------
__global__ __launch_bounds__(256, 2) void pointnet_pool_kernel(
    const float* __restrict__ x, const int* __restrict__ lengths,
    const float* __restrict__ W1, const float* __restrict__ b1,
    const float* __restrict__ W2, const float* __restrict__ b2,
    const float* __restrict__ W3, const float* __restrict__ b3,
    const float* __restrict__ W4,
    float* __restrict__ partials)
{
    const int tid  = threadIdx.x;
    const int gid  = blockIdx.x * 256 + tid;
    const int b    = gid >> 11;        // 2048 points per batch element
    const int n    = gid & 2047;
    const int len  = lengths[b];       // uniform per block (2048 % 256 == 0)
    const int nb0  = (blockIdx.x & 7) * 256;  // block's first point index in b

    __shared__ float wred[4][1024];

    // whole block past the ragged length: write -inf partials, done.
    if (nb0 >= len) {
        for (int i = tid; i < 1024; i += 256)
            partials[(size_t)blockIdx.x * 1024 + i] = -INFINITY;
        return;
    }

    const int wave = tid >> 6, lane = tid & 63;
    const bool wave_active = (nb0 + wave * 64) < len;
    const bool valid = n < len;

    if (wave_active) {
        const float x0 = x[gid * 3 + 0];
        const float x1 = x[gid * 3 + 1];
        const float x2 = x[gid * 3 + 2];

        float h1[64];
#pragma unroll
        for (int c = 0; c < 64; ++c) {
            float v = b1[c];
            v = fmaf(x0, W1[c], v);
            v = fmaf(x1, W1[64 + c], v);
            v = fmaf(x2, W1[128 + c], v);
            h1[c] = lrelu(v);
        }
        float h2[64];
#pragma unroll
        for (int c = 0; c < 64; ++c) {
            float v = b2[c];
#pragma unroll
            for (int k = 0; k < 64; ++k) v = fmaf(h1[k], W2[k * 64 + c], v);
            h2[c] = lrelu(v);
        }
        float h3[128];
#pragma unroll
        for (int c = 0; c < 128; ++c) {
            float v = b3[c];
#pragma unroll
            for (int k = 0; k < 64; ++k) v = fmaf(h2[k], W3[k * 128 + c], v);
            h3[c] = lrelu(v);
        }

        // L4 (128 -> 1024) fused with masked max over points.
        for (int o4 = 0; o4 < 256; ++o4) {
            const float* wp = W4 + o4 * 4;   // wave-uniform -> scalar loads
            float a0 = 0.f, a1 = 0.f, a2 = 0.f, a3 = 0.f;
#pragma unroll
            for (int k = 0; k < 128; ++k) {
                const float h = h3[k];
                a0 = fmaf(h, wp[k * 1024 + 0], a0);
                a1 = fmaf(h, wp[k * 1024 + 1], a1);
                a2 = fmaf(h, wp[k * 1024 + 2], a2);
                a3 = fmaf(h, wp[k * 1024 + 3], a3);
            }
            float r[4] = {a0, a1, a2, a3};
#pragma unroll
            for (int j = 0; j < 4; ++j) {
                float v = valid ? r[j] : -INFINITY;
#pragma unroll
                for (int off = 32; off > 0; off >>= 1)
                    v = fmaxf(v, __shfl_xor(v, off));
                if (lane == 0) wred[wave][o4 * 4 + j] = v;
            }
        }
    } else {
        for (int i = lane; i < 1024; i += 64)
            wred[wave][i] = -INFINITY;
    }
    __syncthreads();

    for (int i = tid; i < 1024; i += 256) {
        float m = fmaxf(fmaxf(wred[0][i], wred[1][i]),
                        fmaxf(wred[2][i], wred[3][i]));
        partials[(size_t)blockIdx.x * 1024 + i] = m;
    }
}

// ---------------------------------------------------------------------------
// Kernel B: reduce 8 block-partials per batch element, add b4, LeakyReLU.
// pooled[b][o] = lrelu(max_j partials[b*8+j][o] + b4[o])
// ---------------------------------------------------------------------------
__global__ __launch_bounds__(256) void reduce_pool_kernel(
    const float* __restrict__ partials, const float* __restrict__ b4,
    float* __restrict__ pooled)
{
    const int b = blockIdx.x;
    for (int i = threadIdx.x; i < 1024; i += 256) {
        float m = -INFINITY;
#pragma unroll
        for (int j = 0; j < 8; ++j)
            m = fmaxf(m, partials[(size_t)(b * 8 + j) * 1024 + i]);
        pooled[(size_t)b * 1024 + i] = lrelu(m + b4[i]);
    }
}

// ---------------------------------------------------------------------------
// Generic small fp32 GEMM: out[M=128, Cout] = act(A[128, K] @ W[K, Cout] + bias)
// Block tile 32 rows x 64 cols, K-tiles of 64 staged in LDS.
// Requires K % 64 == 0, Cout % 64 == 0. grid = (Cout/64, 4).
// ---------------------------------------------------------------------------
__global__ __launch_bounds__(256) void gemm_kernel(
    const float* __restrict__ A, const float* __restrict__ W,
    const float* __restrict__ bias, float* __restrict__ out,
    int K, int Cout, int act)
{
    __shared__ float As[32][66];
    __shared__ float Ws[64][68];

    const int tid = threadIdx.x;
    const int ci = tid & 15;       // -> 4 cols at ci*4
    const int ri = tid >> 4;       // -> 2 rows at ri*2
    const int col0 = blockIdx.x * 64;
    const int row0 = blockIdx.y * 32;

    float acc[2][4] = {{0.f, 0.f, 0.f, 0.f}, {0.f, 0.f, 0.f, 0.f}};

    for (int kt = 0; kt < K; kt += 64) {
#pragma unroll
        for (int j = 0; j < 8; ++j) {            // 32x64 A tile
            int idx = tid + j * 256;
            int r = idx >> 6, k = idx & 63;
            As[r][k] = A[(size_t)(row0 + r) * K + kt + k];
        }
#pragma unroll
        for (int j = 0; j < 16; ++j) {           // 64x64 W tile
            int idx = tid + j * 256;
            int k = idx >> 6, c = idx & 63;
            Ws[k][c] = W[(size_t)(kt + k) * Cout + col0 + c];
        }
        __syncthreads();
#pragma unroll
        for (int k = 0; k < 64; ++k) {
            float a0 = As[ri * 2 + 0][k];
            float a1 = As[ri * 2 + 1][k];
            float4 w = *(const float4*)&Ws[k][ci * 4];
            acc[0][0] = fmaf(a0, w.x, acc[0][0]);
            acc[0][1] = fmaf(a0, w.y, acc[0][1]);
            acc[0][2] = fmaf(a0, w.z, acc[0][2]);
            acc[0][3] = fmaf(a0, w.w, acc[0][3]);
            acc[1][0] = fmaf(a1, w.x, acc[1][0]);
            acc[1][1] = fmaf(a1, w.y, acc[1][1]);
            acc[1][2] = fmaf(a1, w.z, acc[1][2]);
            acc[1][3] = fmaf(a1, w.w, acc[1][3]);
        }
        __syncthreads();
    }

#pragma unroll
    for (int r = 0; r < 2; ++r) {
#pragma unroll
        for (int c = 0; c < 4; ++c) {
            float v = acc[r][c] + bias[col0 + ci * 4 + c];
            if (act) v = lrelu(v);
            out[(size_t)(row0 + ri * 2 + r) * Cout + col0 + ci * 4 + c] = v;
        }
    }
}

// ---------------------------------------------------------------------------
// Reparameterize: z = mu + eps * exp(0.5 * logvar)   (32768 elements)
// ---------------------------------------------------------------------------
__global__ __launch_bounds__(256) void reparam_kernel(
    const float* __restrict__ mu, const float* __restrict__ lv,
    const float* __restrict__ eps, float* __restrict__ z)
{
    const int i = blockIdx.x * 256 + threadIdx.x;
    z[i] = fmaf(eps[i], expf(0.5f * lv[i]), mu[i]);
}

// ---------------------------------------------------------------------------
// BatchNorm1d (training-mode biased batch stats) + LeakyReLU.
// in/out: [128, 1024]; one thread per column. grid = 4 x 256.
// ---------------------------------------------------------------------------
__global__ __launch_bounds__(256) void bn_kernel(
    const float* __restrict__ in, const float* __restrict__ g,
    const float* __restrict__ be, float* __restrict__ out)
{
    const int c = blockIdx.x * 256 + threadIdx.x;
    float s = 0.f, sq = 0.f;
    for (int r = 0; r < 128; ++r) {
        float v = in[(size_t)r * 1024 + c];
        s += v;
        sq = fmaf(v, v, sq);
    }
    const float m   = s * (1.0f / 128.0f);
    const float var = sq * (1.0f / 128.0f) - m * m;
    const float rs  = 1.0f / sqrtf(var + 1e-5f);
    const float gg  = g[c] * rs;
    const float bb  = be[c] - m * gg;
    for (int r = 0; r < 128; ++r) {
        float v = in[(size_t)r * 1024 + c];
        out[(size_t)r * 1024 + c] = lrelu(fmaf(v, gg, bb));
    }
}

// ---------------------------------------------------------------------------
extern "C" void kernel_launch(void* const* d_in, const int* in_sizes, int n_in,
                              void* d_out, int out_size, void* d_ws, size_t ws_size,
                              hipStream_t stream)
{
    const float* x       = (const float*)d_in[0];
    const int*   lengths = (const int*)  d_in[1];
    const float* eps     = (const float*)d_in[2];
    const float* W1  = (const float*)d_in[3];  const float* b1  = (const float*)d_in[4];
    const float* W2  = (const float*)d_in[5];  const float* b2  = (const float*)d_in[6];
    const float* W3  = (const float*)d_in[7];  const float* b3  = (const float*)d_in[8];
    const float* W4  = (const float*)d_in[9];  const float* b4  = (const float*)d_in[10];
    const float* Wf  = (const float*)d_in[11]; const float* bf  = (const float*)d_in[12];
    const float* Wmu = (const float*)d_in[13]; const float* bmu = (const float*)d_in[14];
    const float* Wlv = (const float*)d_in[15]; const float* blv = (const float*)d_in[16];
    const float* Wd1 = (const float*)d_in[17]; const float* bd1 = (const float*)d_in[18];
    const float* g1  = (const float*)d_in[19]; const float* be1 = (const float*)d_in[20];
    const float* Wd2 = (const float*)d_in[21]; const float* bd2 = (const float*)d_in[22];
    const float* g2  = (const float*)d_in[23]; const float* be2 = (const float*)d_in[24];
    const float* Wd3 = (const float*)d_in[25]; const float* bd3 = (const float*)d_in[26];

    float* out = (float*)d_out;
    float* y_out  = out;               // [128,128,3] = 49152
    float* mu_out = out + 49152;       // [128,256]   = 32768
    float* lv_out = out + 81920;       // [128,256]   = 32768

    float* ws = (float*)d_ws;
    float* partials = ws;              // 1024 * 1024 = 1,048,576 floats (4 MB)
    float* pooled   = partials + 1048576;  // 128*1024
    float* ebuf     = pooled + 131072;     // 128*1024
    float* zbuf     = ebuf + 131072;       // 128*256
    float* t1       = zbuf + 32768;        // 128*1024
    float* d1v      = t1 + 131072;         // 128*1024
    float* t2       = d1v + 131072;        // 128*1024
    float* d2v      = t2 + 131072;         // 128*1024

    // 1) fused pointnet MLP + masked max partial pool
    pointnet_pool_kernel<<<1024, 256, 0, stream>>>(
        x, lengths, W1, b1, W2, b2, W3, b3, W4, partials);
    // 2) finish pool: max over 8 partials, + b4, lrelu
    reduce_pool_kernel<<<128, 256, 0, stream>>>(partials, b4, pooled);
    // 3) encoder head: e = lrelu(pooled @ Wf + bf)
    gemm_kernel<<<dim3(16, 4), 256, 0, stream>>>(pooled, Wf, bf, ebuf, 1024, 1024, 1);
    // 4) mu, logvar (straight to d_out)
    gemm_kernel<<<dim3(4, 4), 256, 0, stream>>>(ebuf, Wmu, bmu, mu_out, 1024, 256, 0);
    gemm_kernel<<<dim3(4, 4), 256, 0, stream>>>(ebuf, Wlv, blv, lv_out, 1024, 256, 0);
    // 5) z = mu + eps * exp(0.5*logvar)
    reparam_kernel<<<128, 256, 0, stream>>>(mu_out, lv_out, eps, zbuf);
    // 6) decoder layer 1: Linear -> BN -> lrelu
    gemm_kernel<<<dim3(16, 4), 256, 0, stream>>>(zbuf, Wd1, bd1, t1, 256, 1024, 0);
    bn_kernel<<<4, 256, 0, stream>>>(t1, g1, be1, d1v);
    // 7) decoder layer 2: Linear -> BN -> lrelu
    gemm_kernel<<<dim3(16, 4), 256, 0, stream>>>(d1v, Wd2, bd2, t2, 1024, 1024, 0);
    bn_kernel<<<4, 256, 0, stream>>>(t2, g2, be2, d2v);
    // 8) final linear -> y
    gemm_kernel<<<dim3(6, 4), 256, 0, stream>>>(d2v, Wd3, bd3, y_out, 1024, 384, 0);
}

// Round 2
// 354.136 us; speedup vs baseline: 15.7746x; 15.7746x over previous
//
#include <hip/hip_runtime.h>
#include <hip/hip_bf16.h>
#include <math.h>

#define NEG_SLOPE 0.01f

typedef short short8 __attribute__((ext_vector_type(8)));
typedef float f32x4 __attribute__((ext_vector_type(4)));

__device__ __forceinline__ float lrelu(float v) { return v > 0.0f ? v : NEG_SLOPE * v; }

__device__ __forceinline__ short f2bf(float f) {
    __hip_bfloat16 h = __float2bfloat16(f);
    return __builtin_bit_cast(short, h);
}

// ---------------------------------------------------------------------------
// Transpose W4 [128 k][1024 c] fp32 -> Wt4g [1024 c][128 k] bf16.
// grid (32, 4), 256 threads, 32x32 LDS tiles.
// ---------------------------------------------------------------------------
__global__ __launch_bounds__(256) void transpose_w4_kernel(
    const float* __restrict__ W4, short* __restrict__ Wt4g)
{
    __shared__ float tile[32][33];
    const int c0 = blockIdx.x * 32;
    const int k0 = blockIdx.y * 32;
    const int tid = threadIdx.x;
#pragma unroll
    for (int it = 0; it < 4; ++it) {
        int idx = tid + it * 256;
        int kk = idx >> 5, cc = idx & 31;
        tile[kk][cc] = W4[(size_t)(k0 + kk) * 1024 + c0 + cc];
    }
    __syncthreads();
#pragma unroll
    for (int it = 0; it < 4; ++it) {
        int idx = tid + it * 256;
        int cc = idx >> 5, kk = idx & 31;
        Wt4g[(size_t)(c0 + cc) * 128 + k0 + kk] = f2bf(tile[kk][cc]);
    }
}

// ---------------------------------------------------------------------------
// Fused pointnet: per-point MLP 3->64->64->128 (fp32 VALU) -> bf16 LDS tile ->
// L4 (128->1024) via mfma_f32_16x16x32_bf16 with fused masked max-pool.
// Block = 128 points (one chunk of one batch element). grid = 128*16.
// Output: partials[b][chunk][1024] = max over chunk's valid points of
// dot(h3, W4[:,o])  (bias/lrelu deferred; lrelu monotone).
// ---------------------------------------------------------------------------
__global__ __launch_bounds__(128, 2) void fused_pointnet_kernel(
    const float* __restrict__ x, const int* __restrict__ lengths,
    const float* __restrict__ W1, const float* __restrict__ b1,
    const float* __restrict__ W2, const float* __restrict__ b2,
    const float* __restrict__ W3, const float* __restrict__ b3,
    const short* __restrict__ Wt4g,
    float* __restrict__ partials)
{
    const int tid   = threadIdx.x;
    const int b     = blockIdx.x & 127;
    const int chunk = blockIdx.x >> 7;          // 0..15
    const int len   = lengths[b];

    // LDS: 32KB union region (A-tile, then double-buffered W tiles) + wred.
    __shared__ short uA[16384];                  // 128 rows x 128 k bf16 (32KB)
    __shared__ float wred[2][64];

    const size_t pbase = (size_t)(b * 16 + chunk) * 1024;

    if (chunk * 128 >= len) {                    // whole chunk masked out
        for (int i = tid; i < 1024; i += 128)
            partials[pbase + i] = -INFINITY;
        return;
    }

    const int lane = tid & 63;
    const int w    = tid >> 6;                   // wave id 0/1
    const int gid  = b * 2048 + chunk * 128 + tid;

    // ---- prologue: issue global loads for W-tile 0 (overlaps MLP) ----
    short8 stg[8];
#pragma unroll
    for (int j = 0; j < 8; ++j) {
        int ci = j * 128 + tid;                  // 16B chunk index in tile
        stg[j] = *(const short8*)&Wt4g[ci * 8];  // tile 0 base
    }

    // ---- phase 1: per-point MLP (fp32), h3 -> bf16 swizzled LDS ----
    {
        const float x0 = x[gid * 3 + 0];
        const float x1 = x[gid * 3 + 1];
        const float x2 = x[gid * 3 + 2];

        float h1[64];
#pragma unroll
        for (int c = 0; c < 64; ++c) {
            float v = b1[c];
            v = fmaf(x0, W1[c], v);
            v = fmaf(x1, W1[64 + c], v);
            v = fmaf(x2, W1[128 + c], v);
            h1[c] = lrelu(v);
        }
        float h2[64];
#pragma unroll
        for (int c = 0; c < 64; ++c) {
            float v = b2[c];
#pragma unroll
            for (int k = 0; k < 64; ++k) v = fmaf(h1[k], W2[k * 64 + c], v);
            h2[c] = lrelu(v);
        }
        // h3 in two halves of 64 cols to cap register pressure
#pragma unroll
        for (int half = 0; half < 2; ++half) {
            float hh[64];
#pragma unroll
            for (int c = 0; c < 64; ++c) {
                float v = b3[half * 64 + c];
#pragma unroll
                for (int k = 0; k < 64; ++k)
                    v = fmaf(h2[k], W3[k * 128 + half * 64 + c], v);
                hh[c] = lrelu(v);
            }
#pragma unroll
            for (int q = 0; q < 8; ++q) {
                short8 pv;
#pragma unroll
                for (int e = 0; e < 8; ++e) pv[e] = f2bf(hh[q * 8 + e]);
                int ch = half * 8 + q;           // 16B chunk within the row
                *(short8*)&uA[tid * 128 + ((ch ^ (tid & 7)) * 8)] = pv;
            }
        }
    }
    __syncthreads();

    // ---- extract persistent A fragments (64 VGPRs), then free uA ----
    short8 af[4][4];                             // [m][kstep]
#pragma unroll
    for (int m = 0; m < 4; ++m) {
#pragma unroll
        for (int ks = 0; ks < 4; ++ks) {
            int row = w * 64 + m * 16 + (lane & 15);
            int ch  = (ks * 4 + (lane >> 4)) ^ (row & 7);
            af[m][ks] = *(const short8*)&uA[row * 128 + ch * 8];
        }
    }
    __syncthreads();                             // all extracts done before reuse

    // ---- write W-tile 0 into buffer 0 (swizzled), issue loads for tile 1 ----
#pragma unroll
    for (int j = 0; j < 8; ++j) {
        int ci = j * 128 + tid;
        int row = ci >> 4, ch = ci & 15;
        *(short8*)&uA[row * 128 + ((ch ^ (row & 7)) * 8)] = stg[j];
    }
#pragma unroll
    for (int j = 0; j < 8; ++j) {
        int ci = j * 128 + tid;
        stg[j] = *(const short8*)&Wt4g[8192 + ci * 8];   // tile 1
    }
    __syncthreads();

    // ---- 16 col-tiles of 64 outputs each ----
    for (int t = 0; t < 16; ++t) {
        const short* wb = uA + (t & 1) * 8192;

        f32x4 acc[4][4];
#pragma unroll
        for (int m = 0; m < 4; ++m)
#pragma unroll
            for (int n = 0; n < 4; ++n) acc[m][n] = 0;

#pragma unroll
        for (int ks = 0; ks < 4; ++ks) {
#pragma unroll
            for (int n = 0; n < 4; ++n) {
                int col = n * 16 + (lane & 15);
                int ch  = (ks * 4 + (lane >> 4)) ^ (col & 7);
                short8 bf = *(const short8*)&wb[col * 128 + ch * 8];
#pragma unroll
                for (int m = 0; m < 4; ++m)
                    acc[m][n] = __builtin_amdgcn_mfma_f32_16x16x32_bf16(
                        af[m][ks], bf, acc[m][n], 0, 0, 0);
            }
        }

        // fold masked max over this wave's 64 rows
#pragma unroll
        for (int n = 0; n < 4; ++n) {
            float v = -INFINITY;
#pragma unroll
            for (int m = 0; m < 4; ++m) {
#pragma unroll
                for (int r = 0; r < 4; ++r) {
                    int row_local = w * 64 + m * 16 + (lane >> 4) * 4 + r;
                    bool valid = (chunk * 128 + row_local) < len;
                    v = fmaxf(v, valid ? acc[m][n][r] : -INFINITY);
                }
            }
            v = fmaxf(v, __shfl_xor(v, 16));
            v = fmaxf(v, __shfl_xor(v, 32));
            if (lane < 16) wred[w][n * 16 + lane] = v;
        }

        // stage next tile's registers into the other LDS buffer
        if (t < 15) {
            short* dst = uA + ((t + 1) & 1) * 8192;
#pragma unroll
            for (int j = 0; j < 8; ++j) {
                int ci = j * 128 + tid;
                int row = ci >> 4, ch = ci & 15;
                *(short8*)&dst[row * 128 + ((ch ^ (row & 7)) * 8)] = stg[j];
            }
        }
        __syncthreads();

        if (tid < 64)
            partials[pbase + t * 64 + tid] = fmaxf(wred[0][tid], wred[1][tid]);

        // issue global loads for tile t+2
        if (t < 14) {
#pragma unroll
            for (int j = 0; j < 8; ++j) {
                int ci = j * 128 + tid;
                stg[j] = *(const short8*)&Wt4g[(size_t)(t + 2) * 8192 + ci * 8];
            }
        }
        __syncthreads();
    }
}

// ---------------------------------------------------------------------------
// Reduce 16 chunk-partials per batch element, add b4, LeakyReLU.
// ---------------------------------------------------------------------------
__global__ __launch_bounds__(256) void reduce_pool_kernel(
    const float* __restrict__ partials, const float* __restrict__ b4,
    float* __restrict__ pooled)
{
    const int b = blockIdx.x;
    for (int i = threadIdx.x; i < 1024; i += 256) {
        float m = -INFINITY;
#pragma unroll
        for (int j = 0; j < 16; ++j)
            m = fmaxf(m, partials[(size_t)(b * 16 + j) * 1024 + i]);
        pooled[(size_t)b * 1024 + i] = lrelu(m + b4[i]);
    }
}

// ---------------------------------------------------------------------------
// Generic small fp32 GEMM: out[128, Cout] = act(A[128, K] @ W[K, Cout] + bias)
// ---------------------------------------------------------------------------
__global__ __launch_bounds__(256) void gemm_kernel(
    const float* __restrict__ A, const float* __restrict__ W,
    const float* __restrict__ bias, float* __restrict__ out,
    int K, int Cout, int act)
{
    __shared__ float As[32][66];
    __shared__ float Ws[64][68];

    const int tid = threadIdx.x;
    const int ci = tid & 15;
    const int ri = tid >> 4;
    const int col0 = blockIdx.x * 64;
    const int row0 = blockIdx.y * 32;

    float acc[2][4] = {{0.f, 0.f, 0.f, 0.f}, {0.f, 0.f, 0.f, 0.f}};

    for (int kt = 0; kt < K; kt += 64) {
#pragma unroll
        for (int j = 0; j < 8; ++j) {
            int idx = tid + j * 256;
            int r = idx >> 6, k = idx & 63;
            As[r][k] = A[(size_t)(row0 + r) * K + kt + k];
        }
#pragma unroll
        for (int j = 0; j < 16; ++j) {
            int idx = tid + j * 256;
            int k = idx >> 6, c = idx & 63;
            Ws[k][c] = W[(size_t)(kt + k) * Cout + col0 + c];
        }
        __syncthreads();
#pragma unroll
        for (int k = 0; k < 64; ++k) {
            float a0 = As[ri * 2 + 0][k];
            float a1 = As[ri * 2 + 1][k];
            float4 wv = *(const float4*)&Ws[k][ci * 4];
            acc[0][0] = fmaf(a0, wv.x, acc[0][0]);
            acc[0][1] = fmaf(a0, wv.y, acc[0][1]);
            acc[0][2] = fmaf(a0, wv.z, acc[0][2]);
            acc[0][3] = fmaf(a0, wv.w, acc[0][3]);
            acc[1][0] = fmaf(a1, wv.x, acc[1][0]);
            acc[1][1] = fmaf(a1, wv.y, acc[1][1]);
            acc[1][2] = fmaf(a1, wv.z, acc[1][2]);
            acc[1][3] = fmaf(a1, wv.w, acc[1][3]);
        }
        __syncthreads();
    }

#pragma unroll
    for (int r = 0; r < 2; ++r) {
#pragma unroll
        for (int c = 0; c < 4; ++c) {
            float v = acc[r][c] + bias[col0 + ci * 4 + c];
            if (act) v = lrelu(v);
            out[(size_t)(row0 + ri * 2 + r) * Cout + col0 + ci * 4 + c] = v;
        }
    }
}

__global__ __launch_bounds__(256) void reparam_kernel(
    const float* __restrict__ mu, const float* __restrict__ lv,
    const float* __restrict__ eps, float* __restrict__ z)
{
    const int i = blockIdx.x * 256 + threadIdx.x;
    z[i] = fmaf(eps[i], expf(0.5f * lv[i]), mu[i]);
}

__global__ __launch_bounds__(256) void bn_kernel(
    const float* __restrict__ in, const float* __restrict__ g,
    const float* __restrict__ be, float* __restrict__ out)
{
    const int c = blockIdx.x * 256 + threadIdx.x;
    float s = 0.f, sq = 0.f;
    for (int r = 0; r < 128; ++r) {
        float v = in[(size_t)r * 1024 + c];
        s += v;
        sq = fmaf(v, v, sq);
    }
    const float m   = s * (1.0f / 128.0f);
    const float var = sq * (1.0f / 128.0f) - m * m;
    const float rs  = 1.0f / sqrtf(var + 1e-5f);
    const float gg  = g[c] * rs;
    const float bb  = be[c] - m * gg;
    for (int r = 0; r < 128; ++r) {
        float v = in[(size_t)r * 1024 + c];
        out[(size_t)r * 1024 + c] = lrelu(fmaf(v, gg, bb));
    }
}

// ---------------------------------------------------------------------------
extern "C" void kernel_launch(void* const* d_in, const int* in_sizes, int n_in,
                              void* d_out, int out_size, void* d_ws, size_t ws_size,
                              hipStream_t stream)
{
    const float* x       = (const float*)d_in[0];
    const int*   lengths = (const int*)  d_in[1];
    const float* eps     = (const float*)d_in[2];
    const float* W1  = (const float*)d_in[3];  const float* b1  = (const float*)d_in[4];
    const float* W2  = (const float*)d_in[5];  const float* b2  = (const float*)d_in[6];
    const float* W3  = (const float*)d_in[7];  const float* b3  = (const float*)d_in[8];
    const float* W4  = (const float*)d_in[9];  const float* b4  = (const float*)d_in[10];
    const float* Wf  = (const float*)d_in[11]; const float* bf  = (const float*)d_in[12];
    const float* Wmu = (const float*)d_in[13]; const float* bmu = (const float*)d_in[14];
    const float* Wlv = (const float*)d_in[15]; const float* blv = (const float*)d_in[16];
    const float* Wd1 = (const float*)d_in[17]; const float* bd1 = (const float*)d_in[18];
    const float* g1  = (const float*)d_in[19]; const float* be1 = (const float*)d_in[20];
    const float* Wd2 = (const float*)d_in[21]; const float* bd2 = (const float*)d_in[22];
    const float* g2  = (const float*)d_in[23]; const float* be2 = (const float*)d_in[24];
    const float* Wd3 = (const float*)d_in[25]; const float* bd3 = (const float*)d_in[26];

    float* out = (float*)d_out;
    float* y_out  = out;               // [128,128,3] = 49152
    float* mu_out = out + 49152;       // [128,256]   = 32768
    float* lv_out = out + 81920;       // [128,256]   = 32768

    // workspace layout
    short* Wt4g     = (short*)d_ws;                       // 1024*128 bf16 = 256KB
    float* partials = (float*)((char*)d_ws + 262144);     // 128*16*1024 f32 = 8MB
    float* pooled   = partials + 128 * 16 * 1024;         // 128*1024
    float* ebuf     = pooled + 131072;                    // 128*1024
    float* zbuf     = ebuf + 131072;                      // 128*256
    float* t1       = zbuf + 32768;                       // 128*1024
    float* d1v      = t1 + 131072;                        // 128*1024
    float* t2       = d1v + 131072;                       // 128*1024
    float* d2v      = t2 + 131072;                        // 128*1024

    // 0) one-time (per launch) transpose W4 -> bf16 [1024][128]
    transpose_w4_kernel<<<dim3(32, 4), 256, 0, stream>>>(W4, Wt4g);
    // 1) fused pointnet MLP + bf16 MFMA L4 + masked max partial pool
    fused_pointnet_kernel<<<2048, 128, 0, stream>>>(
        x, lengths, W1, b1, W2, b2, W3, b3, Wt4g, partials);
    // 2) finish pool: max over 16 partials, + b4, lrelu
    reduce_pool_kernel<<<128, 256, 0, stream>>>(partials, b4, pooled);
    // 3) encoder head
    gemm_kernel<<<dim3(16, 4), 256, 0, stream>>>(pooled, Wf, bf, ebuf, 1024, 1024, 1);
    gemm_kernel<<<dim3(4, 4), 256, 0, stream>>>(ebuf, Wmu, bmu, mu_out, 1024, 256, 0);
    gemm_kernel<<<dim3(4, 4), 256, 0, stream>>>(ebuf, Wlv, blv, lv_out, 1024, 256, 0);
    // 4) reparameterize
    reparam_kernel<<<128, 256, 0, stream>>>(mu_out, lv_out, eps, zbuf);
    // 5) decoder
    gemm_kernel<<<dim3(16, 4), 256, 0, stream>>>(zbuf, Wd1, bd1, t1, 256, 1024, 0);
    bn_kernel<<<4, 256, 0, stream>>>(t1, g1, be1, d1v);
    gemm_kernel<<<dim3(16, 4), 256, 0, stream>>>(d1v, Wd2, bd2, t2, 1024, 1024, 0);
    bn_kernel<<<4, 256, 0, stream>>>(t2, g2, be2, d2v);
    gemm_kernel<<<dim3(6, 4), 256, 0, stream>>>(d2v, Wd3, bd3, y_out, 1024, 384, 0);
}

// Round 3
// 255.419 us; speedup vs baseline: 21.8713x; 1.3865x over previous
//
#include <hip/hip_runtime.h>
#include <hip/hip_bf16.h>
#include <math.h>

#define NEG_SLOPE 0.01f

typedef short short8 __attribute__((ext_vector_type(8)));
typedef float f32x4 __attribute__((ext_vector_type(4)));

__device__ __forceinline__ float lrelu(float v) { return v > 0.0f ? v : NEG_SLOPE * v; }

__device__ __forceinline__ short f2bf(float f) {
    __hip_bfloat16 h = __float2bfloat16(f);
    return __builtin_bit_cast(short, h);
}

// ---------------------------------------------------------------------------
// pack_all: convert every MFMA-consumed weight matrix from fp32 [K][N] to
// bf16 "fragment-native" layout: frag f = ((t*K32 + ks)*4 + n), lane l, elem e
//   col = t*64 + n*16 + (l&15), k = ks*32 + (l>>4)*8 + e
//   dst[f*512 + l*8 + e] = bf16(W[k][col])
// so a B-fragment load is one fully-coalesced 1KB global_load_dwordx4 / lane.
// Regions (blocks of 256 thr, 4 frags per block):
//   [0,64)    W4    K=128  N=1024
//   [64,576)  Wf    K=1024 N=1024
//   [576,832) Wmu|Wlv (virtual concat) K=1024 N=512
//   [832,960) Wd1   K=256  N=1024
//   [960,1472) Wd2  K=1024 N=1024
//   [1472,1664) Wd3 K=1024 N=384
// ---------------------------------------------------------------------------
__global__ __launch_bounds__(256) void pack_all(
    const float* __restrict__ W4, const float* __restrict__ Wf,
    const float* __restrict__ Wmu, const float* __restrict__ Wlv,
    const float* __restrict__ Wd1, const float* __restrict__ Wd2,
    const float* __restrict__ Wd3,
    short* __restrict__ F4, short* __restrict__ Ff, short* __restrict__ Fmuvl,
    short* __restrict__ Fd1, short* __restrict__ Fd2, short* __restrict__ Fd3)
{
    int bid = blockIdx.x;
    const float* src = nullptr; short* dst = nullptr; int K = 0, N = 0; int muvl = 0;
    if      (bid < 64)   { src = W4;  dst = F4;    K = 128;  N = 1024; }
    else if (bid < 576)  { src = Wf;  dst = Ff;    K = 1024; N = 1024; bid -= 64; }
    else if (bid < 832)  { src = nullptr; dst = Fmuvl; K = 1024; N = 512; muvl = 1; bid -= 576; }
    else if (bid < 960)  { src = Wd1; dst = Fd1;   K = 256;  N = 1024; bid -= 832; }
    else if (bid < 1472) { src = Wd2; dst = Fd2;   K = 1024; N = 1024; bid -= 960; }
    else                 { src = Wd3; dst = Fd3;   K = 1024; N = 384;  bid -= 1472; }

    const int fragid = bid * 4 + (threadIdx.x >> 6);
    const int lane   = threadIdx.x & 63;
    const int K32    = K >> 5;
    const int t   = fragid / (K32 * 4);
    const int rem = fragid - t * K32 * 4;
    const int ks  = rem >> 2;
    const int n   = rem & 3;
    const int col   = t * 64 + n * 16 + (lane & 15);
    const int kbase = ks * 32 + (lane >> 4) * 8;

    short8 v;
#pragma unroll
    for (int e = 0; e < 8; ++e) {
        float f;
        if (muvl) f = (col < 256) ? Wmu[(size_t)(kbase + e) * 256 + col]
                                  : Wlv[(size_t)(kbase + e) * 256 + col - 256];
        else      f = src[(size_t)(kbase + e) * N + col];
        v[e] = f2bf(f);
    }
    *(short8*)&dst[(size_t)fragid * 512 + lane * 8] = v;
}

// ---------------------------------------------------------------------------
// Fused pointnet: per-point MLP 3->64->64->128 (fp32 VALU, registers) ->
// bf16 LDS transpose -> persistent A-frags in VGPRs -> 16 col-tiles of
// mfma_f32_16x16x32_bf16 with B-frags loaded DIRECTLY from global (L2) --
// no per-tile LDS staging, no per-tile barriers. Masked max folded per tile
// into per-wave LDS rows; one final barrier + cross-wave fold.
// Block = 128 points (chunk), grid = 128 b * 16 chunks.
// ---------------------------------------------------------------------------
__global__ __launch_bounds__(128, 2) void fused_pointnet_kernel(
    const float* __restrict__ x, const int* __restrict__ lengths,
    const float* __restrict__ W1, const float* __restrict__ b1,
    const float* __restrict__ W2, const float* __restrict__ b2,
    const float* __restrict__ W3, const float* __restrict__ b3,
    const short* __restrict__ F4,
    float* __restrict__ partials)
{
    const int tid   = threadIdx.x;
    const int b     = blockIdx.x & 127;
    const int chunk = blockIdx.x >> 7;           // 0..15
    const int len   = lengths[b];

    __shared__ short At[128 * 128];              // 32KB: 128 rows x 128 k bf16
    __shared__ float wred[2][1024];              // 8KB per-wave col maxes

    const size_t pbase = (size_t)(b * 16 + chunk) * 1024;

    if (chunk * 128 >= len) {                    // dead chunk
        for (int i = tid; i < 1024; i += 128)
            partials[pbase + i] = -INFINITY;
        return;
    }

    const int lane = tid & 63;
    const int w    = tid >> 6;
    const int gid  = b * 2048 + chunk * 128 + tid;

    // ---- phase 1: per-point MLP (fp32), h3 -> bf16 swizzled LDS ----
    {
        const float x0 = x[gid * 3 + 0];
        const float x1 = x[gid * 3 + 1];
        const float x2 = x[gid * 3 + 2];

        float h1[64];
#pragma unroll
        for (int c = 0; c < 64; ++c) {
            float v = b1[c];
            v = fmaf(x0, W1[c], v);
            v = fmaf(x1, W1[64 + c], v);
            v = fmaf(x2, W1[128 + c], v);
            h1[c] = lrelu(v);
        }
        float h2[64];
#pragma unroll
        for (int c = 0; c < 64; ++c) {
            float v = b2[c];
#pragma unroll
            for (int k = 0; k < 64; ++k) v = fmaf(h1[k], W2[k * 64 + c], v);
            h2[c] = lrelu(v);
        }
#pragma unroll
        for (int half = 0; half < 2; ++half) {
            float hh[64];
#pragma unroll
            for (int c = 0; c < 64; ++c) {
                float v = b3[half * 64 + c];
#pragma unroll
                for (int k = 0; k < 64; ++k)
                    v = fmaf(h2[k], W3[k * 128 + half * 64 + c], v);
                hh[c] = lrelu(v);
            }
#pragma unroll
            for (int q = 0; q < 8; ++q) {
                short8 pv;
#pragma unroll
                for (int e = 0; e < 8; ++e) pv[e] = f2bf(hh[q * 8 + e]);
                int ch = half * 8 + q;           // logical 16B chunk (k = ch*8+e)
                *(short8*)&At[tid * 128 + ((ch ^ (tid & 7)) * 8)] = pv;
            }
        }
    }
    __syncthreads();

    // ---- persistent A fragments: row = w*64 + m*16 + (lane&15) ----
    short8 af[4][4];
#pragma unroll
    for (int m = 0; m < 4; ++m) {
#pragma unroll
        for (int ks = 0; ks < 4; ++ks) {
            int row = w * 64 + m * 16 + (lane & 15);
            int ch  = (ks * 4 + (lane >> 4)) ^ (row & 7);
            af[m][ks] = *(const short8*)&At[row * 128 + ch * 8];
        }
    }

    // ---- 16 col-tiles; B-frags straight from global (L2-resident) ----
    for (int t = 0; t < 16; ++t) {
        f32x4 acc[4][4];
#pragma unroll
        for (int m = 0; m < 4; ++m)
#pragma unroll
            for (int n = 0; n < 4; ++n) acc[m][n] = 0;

#pragma unroll
        for (int ks = 0; ks < 4; ++ks) {
            short8 bf[4];
#pragma unroll
            for (int n = 0; n < 4; ++n)
                bf[n] = *(const short8*)&F4[(size_t)(((t * 4 + ks) * 4 + n) * 64 + lane) * 8];
#pragma unroll
            for (int n = 0; n < 4; ++n)
#pragma unroll
                for (int m = 0; m < 4; ++m)
                    acc[m][n] = __builtin_amdgcn_mfma_f32_16x16x32_bf16(
                        af[m][ks], bf[n], acc[m][n], 0, 0, 0);
        }

        // masked max over this wave's 64 rows -> wred (no barrier needed)
#pragma unroll
        for (int n = 0; n < 4; ++n) {
            float v = -INFINITY;
#pragma unroll
            for (int m = 0; m < 4; ++m) {
#pragma unroll
                for (int r = 0; r < 4; ++r) {
                    int row_local = w * 64 + m * 16 + (lane >> 4) * 4 + r;
                    bool valid = (chunk * 128 + row_local) < len;
                    v = fmaxf(v, valid ? acc[m][n][r] : -INFINITY);
                }
            }
            v = fmaxf(v, __shfl_xor(v, 16));
            v = fmaxf(v, __shfl_xor(v, 32));
            if (lane < 16) wred[w][t * 64 + n * 16 + lane] = v;
        }
    }
    __syncthreads();

    for (int i = tid; i < 1024; i += 128)
        partials[pbase + i] = fmaxf(wred[0][i], wred[1][i]);
}

// ---------------------------------------------------------------------------
// Reduce 16 chunk-partials, + b4, LeakyReLU -> pooled bf16 [128][1024].
// ---------------------------------------------------------------------------
__global__ __launch_bounds__(256) void reduce_pool_kernel(
    const float* __restrict__ partials, const float* __restrict__ b4,
    short* __restrict__ pooled)
{
    const int b = blockIdx.x;
    for (int i = threadIdx.x; i < 1024; i += 256) {
        float m = -INFINITY;
#pragma unroll
        for (int j = 0; j < 16; ++j)
            m = fmaxf(m, partials[(size_t)(b * 16 + j) * 1024 + i]);
        pooled[(size_t)b * 1024 + i] = f2bf(lrelu(m + b4[i]));
    }
}

// ---------------------------------------------------------------------------
// Generic tail GEMM on MFMA: out[128, Nout-tile] from A (bf16 row-major,
// stride K) and packed Wfrag. 256 thr = 4 waves; wave w owns rows w*32..+31.
// flags: 1 = LeakyReLU, 2 = fused BatchNorm (bias skipped: it cancels),
//        4 = bf16 out, 8 = mu|lv split (blocks with c0>=256 use bias2/outF2).
// ---------------------------------------------------------------------------
__global__ __launch_bounds__(256) void gemm_tail(
    const short* __restrict__ A, const short* __restrict__ Wfrag,
    const float* __restrict__ bias, const float* __restrict__ bias2,
    const float* __restrict__ g, const float* __restrict__ be,
    float* __restrict__ outF, float* __restrict__ outF2,
    short* __restrict__ outB, int K, int Nout, int flags)
{
    __shared__ float bns[4][64];
    __shared__ float bnq[4][64];

    const int tid  = threadIdx.x;
    const int lane = tid & 63;
    const int w    = tid >> 6;
    const int K32  = K >> 5;
    int c0 = blockIdx.x * 64;

    const size_t fragbase = (size_t)blockIdx.x * K32 * 4 * 512;

    if ((flags & 8) && c0 >= 256) {              // logvar half
        bias = bias2; outF = outF2; c0 -= 256;
    }

    f32x4 acc[2][4];
#pragma unroll
    for (int m = 0; m < 2; ++m)
#pragma unroll
        for (int n = 0; n < 4; ++n) acc[m][n] = 0;

    const int arow0 = w * 32 + (lane & 15);
    const int koff  = (lane >> 4) * 8;

    for (int ks = 0; ks < K32; ++ks) {
        short8 af0 = *(const short8*)&A[(size_t)arow0 * K + ks * 32 + koff];
        short8 af1 = *(const short8*)&A[(size_t)(arow0 + 16) * K + ks * 32 + koff];
        short8 bf[4];
#pragma unroll
        for (int n = 0; n < 4; ++n)
            bf[n] = *(const short8*)&Wfrag[fragbase + (size_t)(ks * 4 + n) * 512 + lane * 8];
#pragma unroll
        for (int n = 0; n < 4; ++n) {
            acc[0][n] = __builtin_amdgcn_mfma_f32_16x16x32_bf16(af0, bf[n], acc[0][n], 0, 0, 0);
            acc[1][n] = __builtin_amdgcn_mfma_f32_16x16x32_bf16(af1, bf[n], acc[1][n], 0, 0, 0);
        }
    }

    if (flags & 2) {
        // fused BatchNorm over the block's full 128 rows (bias cancels)
#pragma unroll
        for (int n = 0; n < 4; ++n) {
            float s = 0.f, q = 0.f;
#pragma unroll
            for (int m = 0; m < 2; ++m)
#pragma unroll
                for (int r = 0; r < 4; ++r) {
                    float v = acc[m][n][r];
                    s += v; q = fmaf(v, v, q);
                }
            s += __shfl_xor(s, 16); s += __shfl_xor(s, 32);
            q += __shfl_xor(q, 16); q += __shfl_xor(q, 32);
            if (lane < 16) { bns[w][n * 16 + lane] = s; bnq[w][n * 16 + lane] = q; }
        }
        __syncthreads();
#pragma unroll
        for (int n = 0; n < 4; ++n) {
            int cl = n * 16 + (lane & 15);
            float s = bns[0][cl] + bns[1][cl] + bns[2][cl] + bns[3][cl];
            float q = bnq[0][cl] + bnq[1][cl] + bnq[2][cl] + bnq[3][cl];
            float mean = s * (1.0f / 128.0f);
            float var  = q * (1.0f / 128.0f) - mean * mean;
            float rs   = 1.0f / sqrtf(var + 1e-5f);
            float gg   = g[c0 + cl] * rs;
            float bb   = be[c0 + cl] - mean * gg;
#pragma unroll
            for (int m = 0; m < 2; ++m)
#pragma unroll
                for (int r = 0; r < 4; ++r)
                    acc[m][n][r] = fmaf(acc[m][n][r], gg, bb);
        }
    } else if (bias) {
#pragma unroll
        for (int n = 0; n < 4; ++n) {
            float bv = bias[c0 + n * 16 + (lane & 15)];
#pragma unroll
            for (int m = 0; m < 2; ++m)
#pragma unroll
                for (int r = 0; r < 4; ++r) acc[m][n][r] += bv;
        }
    }

    if (flags & 1) {
#pragma unroll
        for (int m = 0; m < 2; ++m)
#pragma unroll
            for (int n = 0; n < 4; ++n)
#pragma unroll
                for (int r = 0; r < 4; ++r) acc[m][n][r] = lrelu(acc[m][n][r]);
    }

#pragma unroll
    for (int m = 0; m < 2; ++m)
#pragma unroll
        for (int n = 0; n < 4; ++n)
#pragma unroll
            for (int r = 0; r < 4; ++r) {
                int row = w * 32 + m * 16 + (lane >> 4) * 4 + r;
                int col = c0 + n * 16 + (lane & 15);
                if (flags & 4) outB[(size_t)row * Nout + col] = f2bf(acc[m][n][r]);
                else           outF[(size_t)row * Nout + col] = acc[m][n][r];
            }
}

// ---------------------------------------------------------------------------
// Reparameterize: z = mu + eps * exp(0.5*logvar) -> bf16
// ---------------------------------------------------------------------------
__global__ __launch_bounds__(256) void reparam_kernel(
    const float* __restrict__ mu, const float* __restrict__ lv,
    const float* __restrict__ eps, short* __restrict__ z)
{
    const int i = blockIdx.x * 256 + threadIdx.x;
    z[i] = f2bf(fmaf(eps[i], expf(0.5f * lv[i]), mu[i]));
}

// ---------------------------------------------------------------------------
extern "C" void kernel_launch(void* const* d_in, const int* in_sizes, int n_in,
                              void* d_out, int out_size, void* d_ws, size_t ws_size,
                              hipStream_t stream)
{
    const float* x       = (const float*)d_in[0];
    const int*   lengths = (const int*)  d_in[1];
    const float* eps     = (const float*)d_in[2];
    const float* W1  = (const float*)d_in[3];  const float* b1  = (const float*)d_in[4];
    const float* W2  = (const float*)d_in[5];  const float* b2  = (const float*)d_in[6];
    const float* W3  = (const float*)d_in[7];  const float* b3  = (const float*)d_in[8];
    const float* W4  = (const float*)d_in[9];  const float* b4  = (const float*)d_in[10];
    const float* Wf  = (const float*)d_in[11]; const float* bf  = (const float*)d_in[12];
    const float* Wmu = (const float*)d_in[13]; const float* bmu = (const float*)d_in[14];
    const float* Wlv = (const float*)d_in[15]; const float* blv = (const float*)d_in[16];
    const float* Wd1 = (const float*)d_in[17]; const float* bd1 = (const float*)d_in[18];
    const float* g1  = (const float*)d_in[19]; const float* be1 = (const float*)d_in[20];
    const float* Wd2 = (const float*)d_in[21]; const float* bd2 = (const float*)d_in[22];
    const float* g2  = (const float*)d_in[23]; const float* be2 = (const float*)d_in[24];
    const float* Wd3 = (const float*)d_in[25]; const float* bd3 = (const float*)d_in[26];
    (void)bd1; (void)bd2;   // provably cancel inside BatchNorm

    float* out = (float*)d_out;
    float* y_out  = out;               // [128,384]
    float* mu_out = out + 49152;       // [128,256]
    float* lv_out = out + 81920;       // [128,256]

    // ---- workspace layout (bytes) ----
    char* ws = (char*)d_ws;
    short* F4    = (short*)(ws + 0);          //  131072 sh
    short* Ff    = (short*)(ws + 262144);     // 1048576 sh
    short* Fmuvl = (short*)(ws + 2359296);    //  524288 sh
    short* Fd1   = (short*)(ws + 3407872);    //  262144 sh
    short* Fd2   = (short*)(ws + 3932160);    // 1048576 sh
    short* Fd3   = (short*)(ws + 6029312);    //  393216 sh
    float* partials = (float*)(ws + 6815744); // 128*16*1024 f32 = 8MB
    short* pooled = (short*)(ws + 15204352);  // 128*1024 bf16
    short* ebuf   = (short*)(ws + 15466496);  // 128*1024
    short* zbuf   = (short*)(ws + 15728640);  // 128*256
    short* d1v    = (short*)(ws + 15794176);  // 128*1024
    short* d2v    = (short*)(ws + 16056320);  // 128*1024

    // 0) pack all MFMA weights to bf16 fragment layout
    pack_all<<<1664, 256, 0, stream>>>(W4, Wf, Wmu, Wlv, Wd1, Wd2, Wd3,
                                       F4, Ff, Fmuvl, Fd1, Fd2, Fd3);
    // 1) fused pointnet MLP + MFMA L4 + masked max partial pool
    fused_pointnet_kernel<<<2048, 128, 0, stream>>>(
        x, lengths, W1, b1, W2, b2, W3, b3, F4, partials);
    // 2) finish pool (+b4, lrelu) -> bf16
    reduce_pool_kernel<<<128, 256, 0, stream>>>(partials, b4, pooled);
    // 3) encoder head: e = lrelu(pooled @ Wf + bf) -> bf16
    gemm_tail<<<16, 256, 0, stream>>>(pooled, Ff, bf, nullptr, nullptr, nullptr,
                                      nullptr, nullptr, ebuf, 1024, 1024, 1 | 4);
    // 4) mu | logvar in one launch (fp32 to d_out)
    gemm_tail<<<8, 256, 0, stream>>>(ebuf, Fmuvl, bmu, blv, nullptr, nullptr,
                                     mu_out, lv_out, nullptr, 1024, 256, 8);
    // 5) z = mu + eps*exp(0.5*lv) -> bf16
    reparam_kernel<<<128, 256, 0, stream>>>(mu_out, lv_out, eps, zbuf);
    // 6) decoder 1: Linear (bias cancels) + BN + lrelu -> bf16
    gemm_tail<<<16, 256, 0, stream>>>(zbuf, Fd1, nullptr, nullptr, g1, be1,
                                      nullptr, nullptr, d1v, 256, 1024, 1 | 2 | 4);
    // 7) decoder 2
    gemm_tail<<<16, 256, 0, stream>>>(d1v, Fd2, nullptr, nullptr, g2, be2,
                                      nullptr, nullptr, d2v, 1024, 1024, 1 | 2 | 4);
    // 8) final linear -> y (fp32)
    gemm_tail<<<6, 256, 0, stream>>>(d2v, Fd3, bd3, nullptr, nullptr, nullptr,
                                     y_out, nullptr, nullptr, 1024, 384, 0);
}

// Round 4
// 178.007 us; speedup vs baseline: 31.3826x; 1.4349x over previous
//
#include <hip/hip_runtime.h>
#include <hip/hip_bf16.h>
#include <math.h>

#define NEG_SLOPE 0.01f

typedef short short8 __attribute__((ext_vector_type(8)));
typedef float f32x4 __attribute__((ext_vector_type(4)));

__device__ __forceinline__ float lrelu(float v) { return v > 0.0f ? v : NEG_SLOPE * v; }

__device__ __forceinline__ short f2bf(float f) {
    __hip_bfloat16 h = __float2bfloat16(f);
    return __builtin_bit_cast(short, h);
}

// ---------------------------------------------------------------------------
// pack_all: fp32 [K][N] -> bf16 fragment-native layout.
// frag f = ((t*K32 + ks)*4 + n); lane l, elem e:
//   col = t*64 + n*16 + (l&15), k = ks*32 + (l>>4)*8 + e
//   dst[f*512 + l*8 + e] = bf16(W[k][col])
// Block regions (4 frags / 256-thr block):
//   [0,64) W4 | [64,576) Wf | [576,832) Wmu|Wlv | [832,960) Wd1
//   [960,1472) Wd2 | [1472,1664) Wd3 | [1664,1666) W2 | [1666,1670) W3
// ---------------------------------------------------------------------------
__global__ __launch_bounds__(256) void pack_all(
    const float* __restrict__ W4, const float* __restrict__ Wf,
    const float* __restrict__ Wmu, const float* __restrict__ Wlv,
    const float* __restrict__ Wd1, const float* __restrict__ Wd2,
    const float* __restrict__ Wd3, const float* __restrict__ W2,
    const float* __restrict__ W3,
    short* __restrict__ F4, short* __restrict__ Ff, short* __restrict__ Fmuvl,
    short* __restrict__ Fd1, short* __restrict__ Fd2, short* __restrict__ Fd3,
    short* __restrict__ F2, short* __restrict__ F3)
{
    int bid = blockIdx.x;
    const float* src = nullptr; short* dst = nullptr; int K = 0, N = 0; int muvl = 0;
    if      (bid < 64)   { src = W4;  dst = F4;    K = 128;  N = 1024; }
    else if (bid < 576)  { src = Wf;  dst = Ff;    K = 1024; N = 1024; bid -= 64; }
    else if (bid < 832)  { src = nullptr; dst = Fmuvl; K = 1024; N = 512; muvl = 1; bid -= 576; }
    else if (bid < 960)  { src = Wd1; dst = Fd1;   K = 256;  N = 1024; bid -= 832; }
    else if (bid < 1472) { src = Wd2; dst = Fd2;   K = 1024; N = 1024; bid -= 960; }
    else if (bid < 1664) { src = Wd3; dst = Fd3;   K = 1024; N = 384;  bid -= 1472; }
    else if (bid < 1666) { src = W2;  dst = F2;    K = 64;   N = 64;   bid -= 1664; }
    else                 { src = W3;  dst = F3;    K = 64;   N = 128;  bid -= 1666; }

    const int fragid = bid * 4 + (threadIdx.x >> 6);
    const int lane   = threadIdx.x & 63;
    const int K32    = K >> 5;
    const int t   = fragid / (K32 * 4);
    const int rem = fragid - t * K32 * 4;
    const int ks  = rem >> 2;
    const int n   = rem & 3;
    const int col   = t * 64 + n * 16 + (lane & 15);
    const int kbase = ks * 32 + (lane >> 4) * 8;

    short8 v;
#pragma unroll
    for (int e = 0; e < 8; ++e) {
        float f;
        if (muvl) f = (col < 256) ? Wmu[(size_t)(kbase + e) * 256 + col]
                                  : Wlv[(size_t)(kbase + e) * 256 + col - 256];
        else      f = src[(size_t)(kbase + e) * N + col];
        v[e] = f2bf(f);
    }
    *(short8*)&dst[(size_t)fragid * 512 + lane * 8] = v;
}

// ---------------------------------------------------------------------------
// Fused pointnet. Block = 128 points. Phases:
//  P0:  h1 = lrelu(x@W1+b1)  fp32 VALU (192 FMA) -> bf16 LDS Ah1 [128][64]
//  L2:  h2 = lrelu(h1@W2+b2) via MFMA (B-frags from F2, global) -> LDS Ah2
//  L3:  h3 = lrelu(h2@W3+b3) via MFMA (F3) -> LDS At [128][128]
//       (A-frags register-buffered before At overwrite of Ah1/Ah2 overlay)
//  L4:  16 col-tiles of mfma(af, F4-frags streamed from L2-cache) with
//       fused masked max-pool into per-wave wred; final cross-wave fold.
// LDS = At 32KB (overlays Ah1+Ah2) + wred 8KB = 40KB -> 4 blocks/CU.
// ---------------------------------------------------------------------------
__global__ __launch_bounds__(128, 2) void fused_pointnet_kernel(
    const float* __restrict__ x, const int* __restrict__ lengths,
    const float* __restrict__ W1, const float* __restrict__ b1,
    const float* __restrict__ b2, const float* __restrict__ b3,
    const short* __restrict__ F2, const short* __restrict__ F3,
    const short* __restrict__ F4,
    float* __restrict__ partials)
{
    const int tid   = threadIdx.x;
    const int b     = blockIdx.x & 127;
    const int chunk = blockIdx.x >> 7;           // 0..15
    const int len   = lengths[b];

    __shared__ short At[128 * 128];              // 32KB
    __shared__ float wred[2][1024];              // 8KB
    short* Ah1 = At;                             // [128][64] overlays At lo
    short* Ah2 = At + 8192;                      // [128][64] overlays At hi

    const size_t pbase = (size_t)(b * 16 + chunk) * 1024;

    if (chunk * 128 >= len) {                    // dead chunk
        for (int i = tid; i < 1024; i += 128)
            partials[pbase + i] = -INFINITY;
        return;
    }

    const int lane = tid & 63;
    const int w    = tid >> 6;
    const int gid  = b * 2048 + chunk * 128 + tid;

    // ---- P0: h1 (fp32 VALU), bf16 -> Ah1 swizzled ----
    {
        const float x0 = x[gid * 3 + 0];
        const float x1 = x[gid * 3 + 1];
        const float x2 = x[gid * 3 + 2];
#pragma unroll
        for (int q = 0; q < 8; ++q) {
            short8 pv;
#pragma unroll
            for (int e = 0; e < 8; ++e) {
                int c = q * 8 + e;
                float v = b1[c];
                v = fmaf(x0, W1[c], v);
                v = fmaf(x1, W1[64 + c], v);
                v = fmaf(x2, W1[128 + c], v);
                pv[e] = f2bf(lrelu(v));
            }
            *(short8*)&Ah1[tid * 64 + ((q ^ (tid & 7)) * 8)] = pv;
        }
    }
    __syncthreads();

    // ---- L2: h2 = lrelu(h1@W2 + b2), MFMA ----
    {
        short8 a2[4][2];
#pragma unroll
        for (int m = 0; m < 4; ++m)
#pragma unroll
            for (int ks = 0; ks < 2; ++ks) {
                int row = w * 64 + m * 16 + (lane & 15);
                int kch = ks * 4 + (lane >> 4);
                a2[m][ks] = *(const short8*)&Ah1[row * 64 + ((kch ^ (row & 7)) * 8)];
            }
        short8 b2f[2][4];
#pragma unroll
        for (int ks = 0; ks < 2; ++ks)
#pragma unroll
            for (int n = 0; n < 4; ++n)
                b2f[ks][n] = *(const short8*)&F2[(size_t)(ks * 4 + n) * 512 + lane * 8];

        f32x4 acc[4][4];
#pragma unroll
        for (int m = 0; m < 4; ++m)
#pragma unroll
            for (int n = 0; n < 4; ++n) acc[m][n] = 0;
#pragma unroll
        for (int ks = 0; ks < 2; ++ks)
#pragma unroll
            for (int n = 0; n < 4; ++n)
#pragma unroll
                for (int m = 0; m < 4; ++m)
                    acc[m][n] = __builtin_amdgcn_mfma_f32_16x16x32_bf16(
                        a2[m][ks], b2f[ks][n], acc[m][n], 0, 0, 0);

        __syncthreads();   // all Ah1 reads done before Ah2 writes (same 40KB? distinct regions, but keep ordering cheap)
#pragma unroll
        for (int n = 0; n < 4; ++n) {
            int col = n * 16 + (lane & 15);
            float bv = b2[col];
            int colch = col >> 3;
#pragma unroll
            for (int m = 0; m < 4; ++m)
#pragma unroll
                for (int r = 0; r < 4; ++r) {
                    int row = w * 64 + m * 16 + (lane >> 4) * 4 + r;
                    Ah2[row * 64 + ((colch ^ (row & 7)) * 8) + (col & 7)] =
                        f2bf(lrelu(acc[m][n][r] + bv));
                }
        }
    }
    __syncthreads();

    // ---- L3a: buffer A-frags (Ah2) in registers before At overwrite ----
    short8 a3[4][2];
#pragma unroll
    for (int m = 0; m < 4; ++m)
#pragma unroll
        for (int ks = 0; ks < 2; ++ks) {
            int row = w * 64 + m * 16 + (lane & 15);
            int kch = ks * 4 + (lane >> 4);
            a3[m][ks] = *(const short8*)&Ah2[row * 64 + ((kch ^ (row & 7)) * 8)];
        }
    __syncthreads();

    // ---- L3b: h3 = lrelu(h2@W3 + b3) -> At [128][128] swizzled ----
#pragma unroll
    for (int half = 0; half < 2; ++half) {
        short8 b3f[2][4];
#pragma unroll
        for (int ks = 0; ks < 2; ++ks)
#pragma unroll
            for (int n = 0; n < 4; ++n)
                b3f[ks][n] = *(const short8*)&F3[(size_t)(half * 8 + ks * 4 + n) * 512 + lane * 8];

        f32x4 acc[4][4];
#pragma unroll
        for (int m = 0; m < 4; ++m)
#pragma unroll
            for (int n = 0; n < 4; ++n) acc[m][n] = 0;
#pragma unroll
        for (int ks = 0; ks < 2; ++ks)
#pragma unroll
            for (int n = 0; n < 4; ++n)
#pragma unroll
                for (int m = 0; m < 4; ++m)
                    acc[m][n] = __builtin_amdgcn_mfma_f32_16x16x32_bf16(
                        a3[m][ks], b3f[ks][n], acc[m][n], 0, 0, 0);

#pragma unroll
        for (int n = 0; n < 4; ++n) {
            int col = half * 64 + n * 16 + (lane & 15);
            float bv = b3[col];
            int colch = col >> 3;
#pragma unroll
            for (int m = 0; m < 4; ++m)
#pragma unroll
                for (int r = 0; r < 4; ++r) {
                    int row = w * 64 + m * 16 + (lane >> 4) * 4 + r;
                    At[row * 128 + ((colch ^ (row & 7)) * 8) + (col & 7)] =
                        f2bf(lrelu(acc[m][n][r] + bv));
                }
        }
    }
    __syncthreads();

    // ---- L4: persistent A-frags + streamed F4 B-frags + fused max-pool ----
    short8 af[4][4];
#pragma unroll
    for (int m = 0; m < 4; ++m)
#pragma unroll
        for (int ks = 0; ks < 4; ++ks) {
            int row = w * 64 + m * 16 + (lane & 15);
            int ch  = (ks * 4 + (lane >> 4)) ^ (row & 7);
            af[m][ks] = *(const short8*)&At[row * 128 + ch * 8];
        }

    for (int t = 0; t < 16; ++t) {
        f32x4 acc[4][4];
#pragma unroll
        for (int m = 0; m < 4; ++m)
#pragma unroll
            for (int n = 0; n < 4; ++n) acc[m][n] = 0;

#pragma unroll
        for (int ks = 0; ks < 4; ++ks) {
            short8 bf[4];
#pragma unroll
            for (int n = 0; n < 4; ++n)
                bf[n] = *(const short8*)&F4[(size_t)(((t * 4 + ks) * 4 + n) * 64 + lane) * 8];
#pragma unroll
            for (int n = 0; n < 4; ++n)
#pragma unroll
                for (int m = 0; m < 4; ++m)
                    acc[m][n] = __builtin_amdgcn_mfma_f32_16x16x32_bf16(
                        af[m][ks], bf[n], acc[m][n], 0, 0, 0);
        }

#pragma unroll
        for (int n = 0; n < 4; ++n) {
            float v = -INFINITY;
#pragma unroll
            for (int m = 0; m < 4; ++m) {
#pragma unroll
                for (int r = 0; r < 4; ++r) {
                    int row_local = w * 64 + m * 16 + (lane >> 4) * 4 + r;
                    bool valid = (chunk * 128 + row_local) < len;
                    v = fmaxf(v, valid ? acc[m][n][r] : -INFINITY);
                }
            }
            v = fmaxf(v, __shfl_xor(v, 16));
            v = fmaxf(v, __shfl_xor(v, 32));
            if (lane < 16) wred[w][t * 64 + n * 16 + lane] = v;
        }
    }
    __syncthreads();

    for (int i = tid; i < 1024; i += 128)
        partials[pbase + i] = fmaxf(wred[0][i], wred[1][i]);
}

// ---------------------------------------------------------------------------
// Reduce 16 chunk-partials, + b4, LeakyReLU -> pooled bf16.
// ---------------------------------------------------------------------------
__global__ __launch_bounds__(256) void reduce_pool_kernel(
    const float* __restrict__ partials, const float* __restrict__ b4,
    short* __restrict__ pooled)
{
    const int b = blockIdx.x;
    for (int i = threadIdx.x; i < 1024; i += 256) {
        float m = -INFINITY;
#pragma unroll
        for (int j = 0; j < 16; ++j)
            m = fmaxf(m, partials[(size_t)(b * 16 + j) * 1024 + i]);
        pooled[(size_t)b * 1024 + i] = f2bf(lrelu(m + b4[i]));
    }
}

// ---------------------------------------------------------------------------
// Tail GEMM on MFMA. flags: 1=lrelu, 2=fused BN (bias cancels), 4=bf16 out.
// ---------------------------------------------------------------------------
__global__ __launch_bounds__(256) void gemm_tail(
    const short* __restrict__ A, const short* __restrict__ Wfrag,
    const float* __restrict__ bias,
    const float* __restrict__ g, const float* __restrict__ be,
    float* __restrict__ outF, short* __restrict__ outB,
    int K, int Nout, int flags)
{
    __shared__ float bns[4][64];
    __shared__ float bnq[4][64];

    const int tid  = threadIdx.x;
    const int lane = tid & 63;
    const int w    = tid >> 6;
    const int K32  = K >> 5;
    const int c0   = blockIdx.x * 64;
    const size_t fragbase = (size_t)blockIdx.x * K32 * 4 * 512;

    f32x4 acc[2][4];
#pragma unroll
    for (int m = 0; m < 2; ++m)
#pragma unroll
        for (int n = 0; n < 4; ++n) acc[m][n] = 0;

    const int arow0 = w * 32 + (lane & 15);
    const int koff  = (lane >> 4) * 8;

    for (int ks = 0; ks < K32; ++ks) {
        short8 af0 = *(const short8*)&A[(size_t)arow0 * K + ks * 32 + koff];
        short8 af1 = *(const short8*)&A[(size_t)(arow0 + 16) * K + ks * 32 + koff];
        short8 bf[4];
#pragma unroll
        for (int n = 0; n < 4; ++n)
            bf[n] = *(const short8*)&Wfrag[fragbase + (size_t)(ks * 4 + n) * 512 + lane * 8];
#pragma unroll
        for (int n = 0; n < 4; ++n) {
            acc[0][n] = __builtin_amdgcn_mfma_f32_16x16x32_bf16(af0, bf[n], acc[0][n], 0, 0, 0);
            acc[1][n] = __builtin_amdgcn_mfma_f32_16x16x32_bf16(af1, bf[n], acc[1][n], 0, 0, 0);
        }
    }

    if (flags & 2) {
#pragma unroll
        for (int n = 0; n < 4; ++n) {
            float s = 0.f, q = 0.f;
#pragma unroll
            for (int m = 0; m < 2; ++m)
#pragma unroll
                for (int r = 0; r < 4; ++r) {
                    float v = acc[m][n][r];
                    s += v; q = fmaf(v, v, q);
                }
            s += __shfl_xor(s, 16); s += __shfl_xor(s, 32);
            q += __shfl_xor(q, 16); q += __shfl_xor(q, 32);
            if (lane < 16) { bns[w][n * 16 + lane] = s; bnq[w][n * 16 + lane] = q; }
        }
        __syncthreads();
#pragma unroll
        for (int n = 0; n < 4; ++n) {
            int cl = n * 16 + (lane & 15);
            float s = bns[0][cl] + bns[1][cl] + bns[2][cl] + bns[3][cl];
            float q = bnq[0][cl] + bnq[1][cl] + bnq[2][cl] + bnq[3][cl];
            float mean = s * (1.0f / 128.0f);
            float var  = q * (1.0f / 128.0f) - mean * mean;
            float rs   = 1.0f / sqrtf(var + 1e-5f);
            float gg   = g[c0 + cl] * rs;
            float bb   = be[c0 + cl] - mean * gg;
#pragma unroll
            for (int m = 0; m < 2; ++m)
#pragma unroll
                for (int r = 0; r < 4; ++r)
                    acc[m][n][r] = fmaf(acc[m][n][r], gg, bb);
        }
    } else if (bias) {
#pragma unroll
        for (int n = 0; n < 4; ++n) {
            float bv = bias[c0 + n * 16 + (lane & 15)];
#pragma unroll
            for (int m = 0; m < 2; ++m)
#pragma unroll
                for (int r = 0; r < 4; ++r) acc[m][n][r] += bv;
        }
    }

    if (flags & 1) {
#pragma unroll
        for (int m = 0; m < 2; ++m)
#pragma unroll
            for (int n = 0; n < 4; ++n)
#pragma unroll
                for (int r = 0; r < 4; ++r) acc[m][n][r] = lrelu(acc[m][n][r]);
    }

#pragma unroll
    for (int m = 0; m < 2; ++m)
#pragma unroll
        for (int n = 0; n < 4; ++n)
#pragma unroll
            for (int r = 0; r < 4; ++r) {
                int row = w * 32 + m * 16 + (lane >> 4) * 4 + r;
                int col = c0 + n * 16 + (lane & 15);
                if (flags & 4) outB[(size_t)row * Nout + col] = f2bf(acc[m][n][r]);
                else           outF[(size_t)row * Nout + col] = acc[m][n][r];
            }
}

// ---------------------------------------------------------------------------
// mu + logvar + reparameterize, fused. grid = 4 blocks (64 cols each).
// ---------------------------------------------------------------------------
__global__ __launch_bounds__(256) void gemm_muvlz(
    const short* __restrict__ A, const short* __restrict__ Fmuvl,
    const float* __restrict__ bmu, const float* __restrict__ blv,
    const float* __restrict__ eps,
    float* __restrict__ mu_out, float* __restrict__ lv_out,
    short* __restrict__ zbuf)
{
    const int tid  = threadIdx.x;
    const int lane = tid & 63;
    const int w    = tid >> 6;
    const int c0   = blockIdx.x * 64;
    const size_t fb_mu = (size_t)blockIdx.x * 32 * 4 * 512;
    const size_t fb_lv = (size_t)(blockIdx.x + 4) * 32 * 4 * 512;

    f32x4 macc[2][4], lacc[2][4];
#pragma unroll
    for (int m = 0; m < 2; ++m)
#pragma unroll
        for (int n = 0; n < 4; ++n) { macc[m][n] = 0; lacc[m][n] = 0; }

    const int arow0 = w * 32 + (lane & 15);
    const int koff  = (lane >> 4) * 8;

    for (int ks = 0; ks < 32; ++ks) {
        short8 af0 = *(const short8*)&A[(size_t)arow0 * 1024 + ks * 32 + koff];
        short8 af1 = *(const short8*)&A[(size_t)(arow0 + 16) * 1024 + ks * 32 + koff];
#pragma unroll
        for (int n = 0; n < 4; ++n) {
            short8 bm = *(const short8*)&Fmuvl[fb_mu + (size_t)(ks * 4 + n) * 512 + lane * 8];
            short8 bl = *(const short8*)&Fmuvl[fb_lv + (size_t)(ks * 4 + n) * 512 + lane * 8];
            macc[0][n] = __builtin_amdgcn_mfma_f32_16x16x32_bf16(af0, bm, macc[0][n], 0, 0, 0);
            macc[1][n] = __builtin_amdgcn_mfma_f32_16x16x32_bf16(af1, bm, macc[1][n], 0, 0, 0);
            lacc[0][n] = __builtin_amdgcn_mfma_f32_16x16x32_bf16(af0, bl, lacc[0][n], 0, 0, 0);
            lacc[1][n] = __builtin_amdgcn_mfma_f32_16x16x32_bf16(af1, bl, lacc[1][n], 0, 0, 0);
        }
    }

#pragma unroll
    for (int n = 0; n < 4; ++n) {
        int col = c0 + n * 16 + (lane & 15);
        float bmv = bmu[col], blvv = blv[col];
#pragma unroll
        for (int m = 0; m < 2; ++m)
#pragma unroll
            for (int r = 0; r < 4; ++r) {
                int row = w * 32 + m * 16 + (lane >> 4) * 4 + r;
                float mu = macc[m][n][r] + bmv;
                float lv = lacc[m][n][r] + blvv;
                mu_out[(size_t)row * 256 + col] = mu;
                lv_out[(size_t)row * 256 + col] = lv;
                float z = fmaf(eps[(size_t)row * 256 + col], expf(0.5f * lv), mu);
                zbuf[(size_t)row * 256 + col] = f2bf(z);
            }
    }
}

// ---------------------------------------------------------------------------
extern "C" void kernel_launch(void* const* d_in, const int* in_sizes, int n_in,
                              void* d_out, int out_size, void* d_ws, size_t ws_size,
                              hipStream_t stream)
{
    const float* x       = (const float*)d_in[0];
    const int*   lengths = (const int*)  d_in[1];
    const float* eps     = (const float*)d_in[2];
    const float* W1  = (const float*)d_in[3];  const float* b1  = (const float*)d_in[4];
    const float* W2  = (const float*)d_in[5];  const float* b2  = (const float*)d_in[6];
    const float* W3  = (const float*)d_in[7];  const float* b3  = (const float*)d_in[8];
    const float* W4  = (const float*)d_in[9];  const float* b4  = (const float*)d_in[10];
    const float* Wf  = (const float*)d_in[11]; const float* bf  = (const float*)d_in[12];
    const float* Wmu = (const float*)d_in[13]; const float* bmu = (const float*)d_in[14];
    const float* Wlv = (const float*)d_in[15]; const float* blv = (const float*)d_in[16];
    const float* Wd1 = (const float*)d_in[17];
    const float* g1  = (const float*)d_in[19]; const float* be1 = (const float*)d_in[20];
    const float* Wd2 = (const float*)d_in[21];
    const float* g2  = (const float*)d_in[23]; const float* be2 = (const float*)d_in[24];
    const float* Wd3 = (const float*)d_in[25]; const float* bd3 = (const float*)d_in[26];
    // bd1, bd2 provably cancel inside BatchNorm

    float* out = (float*)d_out;
    float* y_out  = out;               // [128,384]
    float* mu_out = out + 49152;       // [128,256]
    float* lv_out = out + 81920;       // [128,256]

    // ---- workspace layout (bytes) ----
    char* ws = (char*)d_ws;
    short* F4    = (short*)(ws + 0);          // 256 frags * 1KB
    short* Ff    = (short*)(ws + 262144);     // 2048 * 1KB
    short* Fmuvl = (short*)(ws + 2359296);    // 1024 * 1KB
    short* Fd1   = (short*)(ws + 3407872);    // 512 * 1KB
    short* Fd2   = (short*)(ws + 3932160);    // 2048 * 1KB
    short* Fd3   = (short*)(ws + 6029312);    // 768 * 1KB
    short* F2    = (short*)(ws + 6815744);    // 8 * 1KB
    short* F3    = (short*)(ws + 6823936);    // 16 * 1KB
    float* partials = (float*)(ws + 6840320); // 128*16*1024 f32 = 8MB
    short* pooled = (short*)(ws + 15228928);  // 128*1024 bf16
    short* ebuf   = (short*)(ws + 15491072);  // 128*1024
    short* zbuf   = (short*)(ws + 15753216);  // 128*256
    short* d1v    = (short*)(ws + 15818752);  // 128*1024
    short* d2v    = (short*)(ws + 16080896);  // 128*1024

    // 0) pack all MFMA weights
    pack_all<<<1670, 256, 0, stream>>>(W4, Wf, Wmu, Wlv, Wd1, Wd2, Wd3, W2, W3,
                                       F4, Ff, Fmuvl, Fd1, Fd2, Fd3, F2, F3);
    // 1) fused pointnet (MFMA L2/L3/L4) + masked max partial pool
    fused_pointnet_kernel<<<2048, 128, 0, stream>>>(
        x, lengths, W1, b1, b2, b3, F2, F3, F4, partials);
    // 2) finish pool (+b4, lrelu) -> bf16
    reduce_pool_kernel<<<128, 256, 0, stream>>>(partials, b4, pooled);
    // 3) e = lrelu(pooled @ Wf + bf) -> bf16
    gemm_tail<<<16, 256, 0, stream>>>(pooled, Ff, bf, nullptr, nullptr,
                                      nullptr, ebuf, 1024, 1024, 1 | 4);
    // 4) mu | logvar | z fused
    gemm_muvlz<<<4, 256, 0, stream>>>(ebuf, Fmuvl, bmu, blv, eps,
                                      mu_out, lv_out, zbuf);
    // 5) decoder 1: Linear + BN + lrelu -> bf16
    gemm_tail<<<16, 256, 0, stream>>>(zbuf, Fd1, nullptr, g1, be1,
                                      nullptr, d1v, 256, 1024, 1 | 2 | 4);
    // 6) decoder 2
    gemm_tail<<<16, 256, 0, stream>>>(d1v, Fd2, nullptr, g2, be2,
                                      nullptr, d2v, 1024, 1024, 1 | 2 | 4);
    // 7) final linear -> y (fp32)
    gemm_tail<<<6, 256, 0, stream>>>(d2v, Fd3, bd3, nullptr, nullptr,
                                     y_out, nullptr, 1024, 384, 0);
}

// Round 5
// 147.818 us; speedup vs baseline: 37.7920x; 1.2042x over previous
//
#include <hip/hip_runtime.h>
#include <hip/hip_bf16.h>
#include <math.h>

#define NEG_SLOPE 0.01f

typedef short short8 __attribute__((ext_vector_type(8)));
typedef float f32x4 __attribute__((ext_vector_type(4)));

__device__ __forceinline__ float lrelu(float v) { return v > 0.0f ? v : NEG_SLOPE * v; }

__device__ __forceinline__ short f2bf(float f) {
    __hip_bfloat16 h = __float2bfloat16(f);
    return __builtin_bit_cast(short, h);
}
__device__ __forceinline__ float bf2f(short s) {
    __hip_bfloat16 h = __builtin_bit_cast(__hip_bfloat16, s);
    return __bfloat162float(h);
}

// ---------------------------------------------------------------------------
// pack_all: fp32 [K][N] -> bf16 fragment-native layout.
// frag f = ((t*K32 + ks)*4 + n); lane l, elem e:
//   col = t*64 + n*16 + (l&15), k = ks*32 + (l>>4)*8 + e
//   dst[f*512 + l*8 + e] = bf16(W[k][col])
// ---------------------------------------------------------------------------
__global__ __launch_bounds__(256) void pack_all(
    const float* __restrict__ W4, const float* __restrict__ Wf,
    const float* __restrict__ Wmu, const float* __restrict__ Wlv,
    const float* __restrict__ Wd1, const float* __restrict__ Wd2,
    const float* __restrict__ Wd3, const float* __restrict__ W2,
    const float* __restrict__ W3,
    short* __restrict__ F4, short* __restrict__ Ff, short* __restrict__ Fmuvl,
    short* __restrict__ Fd1, short* __restrict__ Fd2, short* __restrict__ Fd3,
    short* __restrict__ F2, short* __restrict__ F3)
{
    int bid = blockIdx.x;
    const float* src = nullptr; short* dst = nullptr; int K = 0, N = 0; int muvl = 0;
    if      (bid < 64)   { src = W4;  dst = F4;    K = 128;  N = 1024; }
    else if (bid < 576)  { src = Wf;  dst = Ff;    K = 1024; N = 1024; bid -= 64; }
    else if (bid < 832)  { src = nullptr; dst = Fmuvl; K = 1024; N = 512; muvl = 1; bid -= 576; }
    else if (bid < 960)  { src = Wd1; dst = Fd1;   K = 256;  N = 1024; bid -= 832; }
    else if (bid < 1472) { src = Wd2; dst = Fd2;   K = 1024; N = 1024; bid -= 960; }
    else if (bid < 1664) { src = Wd3; dst = Fd3;   K = 1024; N = 384;  bid -= 1472; }
    else if (bid < 1666) { src = W2;  dst = F2;    K = 64;   N = 64;   bid -= 1664; }
    else                 { src = W3;  dst = F3;    K = 64;   N = 128;  bid -= 1666; }

    const int fragid = bid * 4 + (threadIdx.x >> 6);
    const int lane   = threadIdx.x & 63;
    const int K32    = K >> 5;
    const int t   = fragid / (K32 * 4);
    const int rem = fragid - t * K32 * 4;
    const int ks  = rem >> 2;
    const int n   = rem & 3;
    const int col   = t * 64 + n * 16 + (lane & 15);
    const int kbase = ks * 32 + (lane >> 4) * 8;

    short8 v;
#pragma unroll
    for (int e = 0; e < 8; ++e) {
        float f;
        if (muvl) f = (col < 256) ? Wmu[(size_t)(kbase + e) * 256 + col]
                                  : Wlv[(size_t)(kbase + e) * 256 + col - 256];
        else      f = src[(size_t)(kbase + e) * N + col];
        v[e] = f2bf(f);
    }
    *(short8*)&dst[(size_t)fragid * 512 + lane * 8] = v;
}

// ---------------------------------------------------------------------------
// Fused pointnet, fully wave-independent (ZERO barriers):
//  - each wave owns 64 points (rows) and a private 16KB LDS region.
//  - P0: h1 fp32 VALU -> bf16 LDS; L2/L3 via MFMA (weights from packed F2/F3)
//    with h2/h3 through per-wave LDS overlays (in-wave DS ordering only);
//  - L4: persistent A-frags (64 VGPR) + half-tile double-buffered B-frags
//    streamed from F4 (L2-resident), fused masked max over rows;
//  - per-wave col maxes written directly to global partials (bf16).
// Dead chunks exit immediately (reduce folds only live chunks).
// Block = 128 points; grid = 128 b * 16 chunks; LDS = 32KB -> 5 blocks/CU.
// ---------------------------------------------------------------------------
#define LOADPAIR(BUF, T, P)                                                   \
    _Pragma("unroll")                                                         \
    for (int kk = 0; kk < 2; ++kk)                                            \
        _Pragma("unroll")                                                     \
        for (int n = 0; n < 4; ++n)                                           \
            BUF[kk * 4 + n] = *(const short8*)&F4[                            \
                (size_t)(((((T) * 4 + (P) * 2 + kk) * 4) + n) * 64 + lane) * 8];

#define MFMAPAIR(BUF, KS0)                                                    \
    _Pragma("unroll")                                                         \
    for (int kk = 0; kk < 2; ++kk)                                            \
        _Pragma("unroll")                                                     \
        for (int n = 0; n < 4; ++n)                                           \
            _Pragma("unroll")                                                 \
            for (int m = 0; m < 4; ++m)                                       \
                acc[m][n] = __builtin_amdgcn_mfma_f32_16x16x32_bf16(          \
                    af[m][(KS0) + kk], BUF[kk * 4 + n], acc[m][n], 0, 0, 0);

__global__ __launch_bounds__(128, 2) void fused_pointnet_kernel(
    const float* __restrict__ x, const int* __restrict__ lengths,
    const float* __restrict__ W1, const float* __restrict__ b1,
    const float* __restrict__ b2, const float* __restrict__ b3,
    const short* __restrict__ F2, const short* __restrict__ F3,
    const short* __restrict__ F4,
    short* __restrict__ partials)
{
    const int tid   = threadIdx.x;
    const int b     = blockIdx.x & 127;
    const int chunk = blockIdx.x >> 7;           // 0..15
    const int len   = lengths[b];
    if (chunk * 128 >= len) return;              // dead chunk: write nothing

    __shared__ short At[128 * 128];              // 32KB; 16KB per wave
    const int lane = tid & 63;
    const int w    = tid >> 6;
    short* Aw = At + w * 8192;                   // wave-private region
    const int gid  = b * 2048 + chunk * 128 + tid;

    // ---- P0: h1 = lrelu(x@W1+b1), fp32 VALU -> bf16 swizzled LDS ----
    {
        const float x0 = x[gid * 3 + 0];
        const float x1 = x[gid * 3 + 1];
        const float x2 = x[gid * 3 + 2];
#pragma unroll
        for (int q = 0; q < 8; ++q) {
            short8 pv;
#pragma unroll
            for (int e = 0; e < 8; ++e) {
                int c = q * 8 + e;
                float v = b1[c];
                v = fmaf(x0, W1[c], v);
                v = fmaf(x1, W1[64 + c], v);
                v = fmaf(x2, W1[128 + c], v);
                pv[e] = f2bf(lrelu(v));
            }
            *(short8*)&Aw[lane * 64 + ((q ^ (lane & 7)) * 8)] = pv;  // h1: [0,4096)
        }
    }

    // ---- L2: h2 = lrelu(h1@W2 + b2) via MFMA ----
    {
        short8 a2[4][2];
#pragma unroll
        for (int m = 0; m < 4; ++m)
#pragma unroll
            for (int ks = 0; ks < 2; ++ks) {
                int rl = m * 16 + (lane & 15);
                int kch = ks * 4 + (lane >> 4);
                a2[m][ks] = *(const short8*)&Aw[rl * 64 + ((kch ^ (rl & 7)) * 8)];
            }
        short8 b2f[2][4];
#pragma unroll
        for (int ks = 0; ks < 2; ++ks)
#pragma unroll
            for (int n = 0; n < 4; ++n)
                b2f[ks][n] = *(const short8*)&F2[(size_t)(ks * 4 + n) * 512 + lane * 8];

        f32x4 acc2[4][4];
#pragma unroll
        for (int m = 0; m < 4; ++m)
#pragma unroll
            for (int n = 0; n < 4; ++n) acc2[m][n] = 0;
#pragma unroll
        for (int ks = 0; ks < 2; ++ks)
#pragma unroll
            for (int n = 0; n < 4; ++n)
#pragma unroll
                for (int m = 0; m < 4; ++m)
                    acc2[m][n] = __builtin_amdgcn_mfma_f32_16x16x32_bf16(
                        a2[m][ks], b2f[ks][n], acc2[m][n], 0, 0, 0);

#pragma unroll
        for (int n = 0; n < 4; ++n) {
            int col = n * 16 + (lane & 15);
            float bv = b2[col];
            int colch = col >> 3;
#pragma unroll
            for (int m = 0; m < 4; ++m)
#pragma unroll
                for (int r = 0; r < 4; ++r) {
                    int rl = m * 16 + (lane >> 4) * 4 + r;
                    Aw[4096 + rl * 64 + ((colch ^ (rl & 7)) * 8) + (col & 7)] =
                        f2bf(lrelu(acc2[m][n][r] + bv));      // h2: [4096,8192)
                }
        }
    }

    // ---- L3: h3 = lrelu(h2@W3 + b3) -> full region [0,8192) as [64][128] ----
    short8 a3[4][2];
#pragma unroll
    for (int m = 0; m < 4; ++m)
#pragma unroll
        for (int ks = 0; ks < 2; ++ks) {
            int rl = m * 16 + (lane & 15);
            int kch = ks * 4 + (lane >> 4);
            a3[m][ks] = *(const short8*)&Aw[4096 + rl * 64 + ((kch ^ (rl & 7)) * 8)];
        }
#pragma unroll
    for (int half = 0; half < 2; ++half) {
        short8 b3f[2][4];
#pragma unroll
        for (int ks = 0; ks < 2; ++ks)
#pragma unroll
            for (int n = 0; n < 4; ++n)
                b3f[ks][n] = *(const short8*)&F3[(size_t)(half * 8 + ks * 4 + n) * 512 + lane * 8];

        f32x4 acc3[4][4];
#pragma unroll
        for (int m = 0; m < 4; ++m)
#pragma unroll
            for (int n = 0; n < 4; ++n) acc3[m][n] = 0;
#pragma unroll
        for (int ks = 0; ks < 2; ++ks)
#pragma unroll
            for (int n = 0; n < 4; ++n)
#pragma unroll
                for (int m = 0; m < 4; ++m)
                    acc3[m][n] = __builtin_amdgcn_mfma_f32_16x16x32_bf16(
                        a3[m][ks], b3f[ks][n], acc3[m][n], 0, 0, 0);

#pragma unroll
        for (int n = 0; n < 4; ++n) {
            int col = half * 64 + n * 16 + (lane & 15);
            float bv = b3[col];
            int colch = col >> 3;
#pragma unroll
            for (int m = 0; m < 4; ++m)
#pragma unroll
                for (int r = 0; r < 4; ++r) {
                    int rl = m * 16 + (lane >> 4) * 4 + r;
                    Aw[rl * 128 + ((colch ^ (rl & 7)) * 8) + (col & 7)] =
                        f2bf(lrelu(acc3[m][n][r] + bv));
                }
        }
    }

    // ---- L4: persistent A-frags; B half-tile double-buffer from F4 ----
    short8 af[4][4];
#pragma unroll
    for (int m = 0; m < 4; ++m)
#pragma unroll
        for (int ks = 0; ks < 4; ++ks) {
            int rl = m * 16 + (lane & 15);
            int ch = (ks * 4 + (lane >> 4)) ^ (rl & 7);
            af[m][ks] = *(const short8*)&Aw[rl * 128 + ch * 8];
        }

    const size_t pb = ((size_t)(b * 16 + chunk) * 2 + w) * 1024;

    short8 bufA[8], bufB[8];
    LOADPAIR(bufA, 0, 0);
    for (int t = 0; t < 16; ++t) {
        f32x4 acc[4][4];
#pragma unroll
        for (int m = 0; m < 4; ++m)
#pragma unroll
            for (int n = 0; n < 4; ++n) acc[m][n] = 0;

        LOADPAIR(bufB, t, 1);          // pair 1 in flight during pair 0 MFMA
        MFMAPAIR(bufA, 0);
        if (t < 15) LOADPAIR(bufA, t + 1, 0);   // next tile's pair 0 in flight
        MFMAPAIR(bufB, 2);

        // masked max over this wave's 64 rows -> global partials (bf16)
#pragma unroll
        for (int n = 0; n < 4; ++n) {
            float v = -INFINITY;
#pragma unroll
            for (int m = 0; m < 4; ++m)
#pragma unroll
                for (int r = 0; r < 4; ++r) {
                    int rloc = w * 64 + m * 16 + (lane >> 4) * 4 + r;
                    bool valid = (chunk * 128 + rloc) < len;
                    v = fmaxf(v, valid ? acc[m][n][r] : -INFINITY);
                }
            v = fmaxf(v, __shfl_xor(v, 16));
            v = fmaxf(v, __shfl_xor(v, 32));
            if (lane < 16) partials[pb + t * 64 + n * 16 + lane] = f2bf(v);
        }
    }
}

// ---------------------------------------------------------------------------
// Reduce live chunk/wave partials (bf16), + b4, LeakyReLU -> pooled bf16.
// ---------------------------------------------------------------------------
__global__ __launch_bounds__(256) void reduce_pool_kernel(
    const short* __restrict__ partials, const int* __restrict__ lengths,
    const float* __restrict__ b4, short* __restrict__ pooled)
{
    const int b = blockIdx.x;
    const int nlive = (lengths[b] + 127) >> 7;   // >=1
    for (int i = threadIdx.x; i < 1024; i += 256) {
        float m = -INFINITY;
        for (int j = 0; j < nlive; ++j) {
            m = fmaxf(m, bf2f(partials[((size_t)(b * 16 + j) * 2 + 0) * 1024 + i]));
            m = fmaxf(m, bf2f(partials[((size_t)(b * 16 + j) * 2 + 1) * 1024 + i]));
        }
        pooled[(size_t)b * 1024 + i] = f2bf(lrelu(m + b4[i]));
    }
}

// ---------------------------------------------------------------------------
// Tail GEMM on MFMA, 32-col blocks, K-prefetch ping-pong.
// MF=2: M=128 (4 waves x 32 rows), supports fused BN. grid (Nout/32).
// MF=1: M=64 per blockIdx.y (4 waves x 16 rows). grid (Nout/32, 2).
// flags: 1=lrelu, 2=fused BN (bias cancels; MF=2 only), 4=bf16 out.
// ---------------------------------------------------------------------------
template<int MF>
__global__ __launch_bounds__(256) void gemm_tail(
    const short* __restrict__ A, const short* __restrict__ Wfrag,
    const float* __restrict__ bias,
    const float* __restrict__ g, const float* __restrict__ be,
    float* __restrict__ outF, short* __restrict__ outB,
    int K, int Nout, int flags)
{
    __shared__ float bns[4][32];
    __shared__ float bnq[4][32];

    const int tid = threadIdx.x, lane = tid & 63, w = tid >> 6;
    const int K32 = K >> 5;                      // even (8 or 32)
    const int c0  = blockIdx.x * 32;
    const int tt  = blockIdx.x >> 1;
    const int hf  = blockIdx.x & 1;
    const int row0  = (MF == 2) ? 0 : blockIdx.y * 64;
    const int arow0 = row0 + w * (MF * 16) + (lane & 15);
    const int koff  = (lane >> 4) * 8;

    f32x4 acc[MF][2];
#pragma unroll
    for (int m = 0; m < MF; ++m) { acc[m][0] = 0; acc[m][1] = 0; }

    short8 aC[MF], bC[2], aN[MF], bN[2];
#pragma unroll
    for (int m = 0; m < MF; ++m)
        aC[m] = *(const short8*)&A[(size_t)(arow0 + m * 16) * K + koff];
#pragma unroll
    for (int n = 0; n < 2; ++n)
        bC[n] = *(const short8*)&Wfrag[(size_t)((tt * K32) * 4 + hf * 2 + n) * 512 + lane * 8];

    for (int ks = 0; ks < K32; ks += 2) {
#pragma unroll
        for (int m = 0; m < MF; ++m)
            aN[m] = *(const short8*)&A[(size_t)(arow0 + m * 16) * K + (ks + 1) * 32 + koff];
#pragma unroll
        for (int n = 0; n < 2; ++n)
            bN[n] = *(const short8*)&Wfrag[(size_t)((tt * K32 + ks + 1) * 4 + hf * 2 + n) * 512 + lane * 8];
#pragma unroll
        for (int n = 0; n < 2; ++n)
#pragma unroll
            for (int m = 0; m < MF; ++m)
                acc[m][n] = __builtin_amdgcn_mfma_f32_16x16x32_bf16(aC[m], bC[n], acc[m][n], 0, 0, 0);
        if (ks + 2 < K32) {
#pragma unroll
            for (int m = 0; m < MF; ++m)
                aC[m] = *(const short8*)&A[(size_t)(arow0 + m * 16) * K + (ks + 2) * 32 + koff];
#pragma unroll
            for (int n = 0; n < 2; ++n)
                bC[n] = *(const short8*)&Wfrag[(size_t)((tt * K32 + ks + 2) * 4 + hf * 2 + n) * 512 + lane * 8];
        }
#pragma unroll
        for (int n = 0; n < 2; ++n)
#pragma unroll
            for (int m = 0; m < MF; ++m)
                acc[m][n] = __builtin_amdgcn_mfma_f32_16x16x32_bf16(aN[m], bN[n], acc[m][n], 0, 0, 0);
    }

    if ((flags & 2) && MF == 2) {
#pragma unroll
        for (int n = 0; n < 2; ++n) {
            float s = 0.f, q = 0.f;
#pragma unroll
            for (int m = 0; m < MF; ++m)
#pragma unroll
                for (int r = 0; r < 4; ++r) {
                    float v = acc[m][n][r];
                    s += v; q = fmaf(v, v, q);
                }
            s += __shfl_xor(s, 16); s += __shfl_xor(s, 32);
            q += __shfl_xor(q, 16); q += __shfl_xor(q, 32);
            if (lane < 16) { bns[w][n * 16 + lane] = s; bnq[w][n * 16 + lane] = q; }
        }
        __syncthreads();
#pragma unroll
        for (int n = 0; n < 2; ++n) {
            int cl = n * 16 + (lane & 15);
            float s = bns[0][cl] + bns[1][cl] + bns[2][cl] + bns[3][cl];
            float q = bnq[0][cl] + bnq[1][cl] + bnq[2][cl] + bnq[3][cl];
            float mean = s * (1.0f / 128.0f);
            float var  = q * (1.0f / 128.0f) - mean * mean;
            float rs   = 1.0f / sqrtf(var + 1e-5f);
            float gg   = g[c0 + cl] * rs;
            float bb   = be[c0 + cl] - mean * gg;
#pragma unroll
            for (int m = 0; m < MF; ++m)
#pragma unroll
                for (int r = 0; r < 4; ++r)
                    acc[m][n][r] = fmaf(acc[m][n][r], gg, bb);
        }
    } else if (bias) {
#pragma unroll
        for (int n = 0; n < 2; ++n) {
            float bv = bias[c0 + n * 16 + (lane & 15)];
#pragma unroll
            for (int m = 0; m < MF; ++m)
#pragma unroll
                for (int r = 0; r < 4; ++r) acc[m][n][r] += bv;
        }
    }

    if (flags & 1) {
#pragma unroll
        for (int m = 0; m < MF; ++m)
#pragma unroll
            for (int n = 0; n < 2; ++n)
#pragma unroll
                for (int r = 0; r < 4; ++r) acc[m][n][r] = lrelu(acc[m][n][r]);
    }

#pragma unroll
    for (int m = 0; m < MF; ++m)
#pragma unroll
        for (int n = 0; n < 2; ++n)
#pragma unroll
            for (int r = 0; r < 4; ++r) {
                int row = row0 + w * (MF * 16) + m * 16 + (lane >> 4) * 4 + r;
                int col = c0 + n * 16 + (lane & 15);
                if (flags & 4) outB[(size_t)row * Nout + col] = f2bf(acc[m][n][r]);
                else           outF[(size_t)row * Nout + col] = acc[m][n][r];
            }
}

// ---------------------------------------------------------------------------
// mu + logvar + reparameterize, fused. grid (8, 2): 32 cols x 64 rows.
// ---------------------------------------------------------------------------
__global__ __launch_bounds__(256) void gemm_muvlz(
    const short* __restrict__ A, const short* __restrict__ Fmuvl,
    const float* __restrict__ bmu, const float* __restrict__ blv,
    const float* __restrict__ eps,
    float* __restrict__ mu_out, float* __restrict__ lv_out,
    short* __restrict__ zbuf)
{
    const int tid = threadIdx.x, lane = tid & 63, w = tid >> 6;
    const int c0 = blockIdx.x * 32;
    const int tt = blockIdx.x >> 1;
    const int hf = blockIdx.x & 1;
    const int row0 = blockIdx.y * 64;
    const int arow = row0 + w * 16 + (lane & 15);
    const int koff = (lane >> 4) * 8;

    f32x4 macc[2], lacc[2];
#pragma unroll
    for (int n = 0; n < 2; ++n) { macc[n] = 0; lacc[n] = 0; }

    short8 aC, bmC[2], blC[2], aN, bmN[2], blN[2];
    aC = *(const short8*)&A[(size_t)arow * 1024 + koff];
#pragma unroll
    for (int n = 0; n < 2; ++n) {
        bmC[n] = *(const short8*)&Fmuvl[(size_t)((tt * 32) * 4 + hf * 2 + n) * 512 + lane * 8];
        blC[n] = *(const short8*)&Fmuvl[(size_t)(((tt + 4) * 32) * 4 + hf * 2 + n) * 512 + lane * 8];
    }

    for (int ks = 0; ks < 32; ks += 2) {
        aN = *(const short8*)&A[(size_t)arow * 1024 + (ks + 1) * 32 + koff];
#pragma unroll
        for (int n = 0; n < 2; ++n) {
            bmN[n] = *(const short8*)&Fmuvl[(size_t)((tt * 32 + ks + 1) * 4 + hf * 2 + n) * 512 + lane * 8];
            blN[n] = *(const short8*)&Fmuvl[(size_t)(((tt + 4) * 32 + ks + 1) * 4 + hf * 2 + n) * 512 + lane * 8];
        }
#pragma unroll
        for (int n = 0; n < 2; ++n) {
            macc[n] = __builtin_amdgcn_mfma_f32_16x16x32_bf16(aC, bmC[n], macc[n], 0, 0, 0);
            lacc[n] = __builtin_amdgcn_mfma_f32_16x16x32_bf16(aC, blC[n], lacc[n], 0, 0, 0);
        }
        if (ks + 2 < 32) {
            aC = *(const short8*)&A[(size_t)arow * 1024 + (ks + 2) * 32 + koff];
#pragma unroll
            for (int n = 0; n < 2; ++n) {
                bmC[n] = *(const short8*)&Fmuvl[(size_t)((tt * 32 + ks + 2) * 4 + hf * 2 + n) * 512 + lane * 8];
                blC[n] = *(const short8*)&Fmuvl[(size_t)(((tt + 4) * 32 + ks + 2) * 4 + hf * 2 + n) * 512 + lane * 8];
            }
        }
#pragma unroll
        for (int n = 0; n < 2; ++n) {
            macc[n] = __builtin_amdgcn_mfma_f32_16x16x32_bf16(aN, bmN[n], macc[n], 0, 0, 0);
            lacc[n] = __builtin_amdgcn_mfma_f32_16x16x32_bf16(aN, blN[n], lacc[n], 0, 0, 0);
        }
    }

#pragma unroll
    for (int n = 0; n < 2; ++n) {
        int col = c0 + n * 16 + (lane & 15);
        float bmv = bmu[col], blvv = blv[col];
#pragma unroll
        for (int r = 0; r < 4; ++r) {
            int row = row0 + w * 16 + (lane >> 4) * 4 + r;
            float mu = macc[n][r] + bmv;
            float lv = lacc[n][r] + blvv;
            mu_out[(size_t)row * 256 + col] = mu;
            lv_out[(size_t)row * 256 + col] = lv;
            float z = fmaf(eps[(size_t)row * 256 + col], expf(0.5f * lv), mu);
            zbuf[(size_t)row * 256 + col] = f2bf(z);
        }
    }
}

// ---------------------------------------------------------------------------
extern "C" void kernel_launch(void* const* d_in, const int* in_sizes, int n_in,
                              void* d_out, int out_size, void* d_ws, size_t ws_size,
                              hipStream_t stream)
{
    const float* x       = (const float*)d_in[0];
    const int*   lengths = (const int*)  d_in[1];
    const float* eps     = (const float*)d_in[2];
    const float* W1  = (const float*)d_in[3];  const float* b1  = (const float*)d_in[4];
    const float* W2  = (const float*)d_in[5];  const float* b2  = (const float*)d_in[6];
    const float* W3  = (const float*)d_in[7];  const float* b3  = (const float*)d_in[8];
    const float* W4  = (const float*)d_in[9];  const float* b4  = (const float*)d_in[10];
    const float* Wf  = (const float*)d_in[11]; const float* bf  = (const float*)d_in[12];
    const float* Wmu = (const float*)d_in[13]; const float* bmu = (const float*)d_in[14];
    const float* Wlv = (const float*)d_in[15]; const float* blv = (const float*)d_in[16];
    const float* Wd1 = (const float*)d_in[17];
    const float* g1  = (const float*)d_in[19]; const float* be1 = (const float*)d_in[20];
    const float* Wd2 = (const float*)d_in[21];
    const float* g2  = (const float*)d_in[23]; const float* be2 = (const float*)d_in[24];
    const float* Wd3 = (const float*)d_in[25]; const float* bd3 = (const float*)d_in[26];
    // bd1, bd2 provably cancel inside BatchNorm

    float* out = (float*)d_out;
    float* y_out  = out;               // [128,384]
    float* mu_out = out + 49152;       // [128,256]
    float* lv_out = out + 81920;       // [128,256]

    // ---- workspace layout (bytes) ----
    char* ws = (char*)d_ws;
    short* F4    = (short*)(ws + 0);          // 256 frags * 1KB
    short* Ff    = (short*)(ws + 262144);     // 2048 * 1KB
    short* Fmuvl = (short*)(ws + 2359296);    // 1024 * 1KB
    short* Fd1   = (short*)(ws + 3407872);    // 512 * 1KB
    short* Fd2   = (short*)(ws + 3932160);    // 2048 * 1KB
    short* Fd3   = (short*)(ws + 6029312);    // 768 * 1KB
    short* F2    = (short*)(ws + 6815744);    // 8 * 1KB
    short* F3    = (short*)(ws + 6823936);    // 16 * 1KB
    short* partials = (short*)(ws + 6840320); // 128*16*2*1024 bf16 = 8MB
    short* pooled = (short*)(ws + 15228928);  // 128*1024 bf16
    short* ebuf   = (short*)(ws + 15491072);  // 128*1024
    short* zbuf   = (short*)(ws + 15753216);  // 128*256
    short* d1v    = (short*)(ws + 15818752);  // 128*1024
    short* d2v    = (short*)(ws + 16080896);  // 128*1024

    // 0) pack all MFMA weights
    pack_all<<<1670, 256, 0, stream>>>(W4, Wf, Wmu, Wlv, Wd1, Wd2, Wd3, W2, W3,
                                       F4, Ff, Fmuvl, Fd1, Fd2, Fd3, F2, F3);
    // 1) fused pointnet (barrier-free, MFMA L2/L3/L4) + masked max partials
    fused_pointnet_kernel<<<2048, 128, 0, stream>>>(
        x, lengths, W1, b1, b2, b3, F2, F3, F4, partials);
    // 2) finish pool (live chunks only, +b4, lrelu) -> bf16
    reduce_pool_kernel<<<128, 256, 0, stream>>>(partials, lengths, b4, pooled);
    // 3) e = lrelu(pooled @ Wf + bf) -> bf16
    gemm_tail<1><<<dim3(32, 2), 256, 0, stream>>>(pooled, Ff, bf, nullptr, nullptr,
                                                  nullptr, ebuf, 1024, 1024, 1 | 4);
    // 4) mu | logvar | z fused
    gemm_muvlz<<<dim3(8, 2), 256, 0, stream>>>(ebuf, Fmuvl, bmu, blv, eps,
                                               mu_out, lv_out, zbuf);
    // 5) decoder 1: Linear + BN + lrelu -> bf16
    gemm_tail<2><<<32, 256, 0, stream>>>(zbuf, Fd1, nullptr, g1, be1,
                                         nullptr, d1v, 256, 1024, 1 | 2 | 4);
    // 6) decoder 2
    gemm_tail<2><<<32, 256, 0, stream>>>(d1v, Fd2, nullptr, g2, be2,
                                         nullptr, d2v, 1024, 1024, 1 | 2 | 4);
    // 7) final linear -> y (fp32)
    gemm_tail<1><<<dim3(12, 2), 256, 0, stream>>>(d2v, Fd3, bd3, nullptr, nullptr,
                                                  y_out, nullptr, 1024, 384, 0);
}

// Round 6
// 144.210 us; speedup vs baseline: 38.7374x; 1.0250x over previous
//
#include <hip/hip_runtime.h>
#include <hip/hip_bf16.h>
#include <math.h>

#define NEG_SLOPE 0.01f

typedef short short8 __attribute__((ext_vector_type(8)));
typedef float f32x4 __attribute__((ext_vector_type(4)));

__device__ __forceinline__ float lrelu(float v) { return v > 0.0f ? v : NEG_SLOPE * v; }

__device__ __forceinline__ short f2bf(float f) {
    __hip_bfloat16 h = __float2bfloat16(f);
    return __builtin_bit_cast(short, h);
}
__device__ __forceinline__ float bf2f(short s) {
    __hip_bfloat16 h = __builtin_bit_cast(__hip_bfloat16, s);
    return __bfloat162float(h);
}

// ---------------------------------------------------------------------------
// pack_all: fp32 [K][N] -> bf16 fragment-native layout.
// frag f = ((t*K32 + ks)*4 + n); lane l, elem e:
//   col = t*64 + n*16 + (l&15), k = ks*32 + (l>>4)*8 + e
//   dst[f*512 + l*8 + e] = bf16(W[k][col])
// ---------------------------------------------------------------------------
__global__ __launch_bounds__(256) void pack_all(
    const float* __restrict__ W4, const float* __restrict__ Wf,
    const float* __restrict__ Wmu, const float* __restrict__ Wlv,
    const float* __restrict__ Wd1, const float* __restrict__ Wd2,
    const float* __restrict__ Wd3, const float* __restrict__ W2,
    const float* __restrict__ W3,
    short* __restrict__ F4, short* __restrict__ Ff, short* __restrict__ Fmuvl,
    short* __restrict__ Fd1, short* __restrict__ Fd2, short* __restrict__ Fd3,
    short* __restrict__ F2, short* __restrict__ F3)
{
    int bid = blockIdx.x;
    const float* src = nullptr; short* dst = nullptr; int K = 0, N = 0; int muvl = 0;
    if      (bid < 64)   { src = W4;  dst = F4;    K = 128;  N = 1024; }
    else if (bid < 576)  { src = Wf;  dst = Ff;    K = 1024; N = 1024; bid -= 64; }
    else if (bid < 832)  { src = nullptr; dst = Fmuvl; K = 1024; N = 512; muvl = 1; bid -= 576; }
    else if (bid < 960)  { src = Wd1; dst = Fd1;   K = 256;  N = 1024; bid -= 832; }
    else if (bid < 1472) { src = Wd2; dst = Fd2;   K = 1024; N = 1024; bid -= 960; }
    else if (bid < 1664) { src = Wd3; dst = Fd3;   K = 1024; N = 384;  bid -= 1472; }
    else if (bid < 1666) { src = W2;  dst = F2;    K = 64;   N = 64;   bid -= 1664; }
    else                 { src = W3;  dst = F3;    K = 64;   N = 128;  bid -= 1666; }

    const int fragid = bid * 4 + (threadIdx.x >> 6);
    const int lane   = threadIdx.x & 63;
    const int K32    = K >> 5;
    const int t   = fragid / (K32 * 4);
    const int rem = fragid - t * K32 * 4;
    const int ks  = rem >> 2;
    const int n   = rem & 3;
    const int col   = t * 64 + n * 16 + (lane & 15);
    const int kbase = ks * 32 + (lane >> 4) * 8;

    short8 v;
#pragma unroll
    for (int e = 0; e < 8; ++e) {
        float f;
        if (muvl) f = (col < 256) ? Wmu[(size_t)(kbase + e) * 256 + col]
                                  : Wlv[(size_t)(kbase + e) * 256 + col - 256];
        else      f = src[(size_t)(kbase + e) * N + col];
        v[e] = f2bf(f);
    }
    *(short8*)&dst[(size_t)fragid * 512 + lane * 8] = v;
}

// ---------------------------------------------------------------------------
// Fused pointnet v3: block = 256 points (4 waves x 64 rows) of one batch elem.
//  P0-L3: wave-private MLP via fp32 VALU + MFMA, staging in 16KB/wave LDS.
//  L4: F4 col-tiles staged into LDS ONCE PER BLOCK (reg-staged double buffer
//      overlaying waves 0/1's staging), all 4 waves consume via ds_read_b128.
//      One __syncthreads per tile; next tile's global loads issued right after
//      the sync so they complete under the MFMA phase.
//  Max epilogue: full blocks -> plain fmax tree; partial -> precomputed
//      madd[m][r] in {0,-inf} adds (no per-element cmp/cndmask).
// LDS = 64KB -> 2 blocks/CU. grid = 128 b * 8 superchunks.
// ---------------------------------------------------------------------------
__global__ __launch_bounds__(256, 2) void fused_pointnet_kernel(
    const float* __restrict__ x, const int* __restrict__ lengths,
    const float* __restrict__ W1, const float* __restrict__ b1,
    const float* __restrict__ b2, const float* __restrict__ b3,
    const short* __restrict__ F2, const short* __restrict__ F3,
    const short* __restrict__ F4,
    short* __restrict__ partials)
{
    const int tid = threadIdx.x;
    const int b   = blockIdx.x & 127;
    const int sc  = blockIdx.x >> 7;             // 0..7 (256-pt superchunk)
    const int len = lengths[b];
    if (sc * 256 >= len) return;                 // dead superchunk

    __shared__ short S[32768];                   // 64KB
    const int lane = tid & 63;
    const int w    = tid >> 6;
    short* Aw = S + w * 8192;                    // wave-private 16KB staging
    const int gid = b * 2048 + sc * 256 + tid;

    // ---- P0: h1 = lrelu(x@W1+b1), fp32 VALU -> bf16 swizzled LDS ----
    {
        const float x0 = x[gid * 3 + 0];
        const float x1 = x[gid * 3 + 1];
        const float x2 = x[gid * 3 + 2];
#pragma unroll
        for (int q = 0; q < 8; ++q) {
            short8 pv;
#pragma unroll
            for (int e = 0; e < 8; ++e) {
                int c = q * 8 + e;
                float v = b1[c];
                v = fmaf(x0, W1[c], v);
                v = fmaf(x1, W1[64 + c], v);
                v = fmaf(x2, W1[128 + c], v);
                pv[e] = f2bf(lrelu(v));
            }
            *(short8*)&Aw[lane * 64 + ((q ^ (lane & 7)) * 8)] = pv;  // h1 [0,4096)
        }
    }

    // ---- L2: h2 = lrelu(h1@W2 + b2) via MFMA ----
    {
        short8 a2[4][2];
#pragma unroll
        for (int m = 0; m < 4; ++m)
#pragma unroll
            for (int ks = 0; ks < 2; ++ks) {
                int rl = m * 16 + (lane & 15);
                int kch = ks * 4 + (lane >> 4);
                a2[m][ks] = *(const short8*)&Aw[rl * 64 + ((kch ^ (rl & 7)) * 8)];
            }
        short8 b2f[2][4];
#pragma unroll
        for (int ks = 0; ks < 2; ++ks)
#pragma unroll
            for (int n = 0; n < 4; ++n)
                b2f[ks][n] = *(const short8*)&F2[(size_t)(ks * 4 + n) * 512 + lane * 8];

        f32x4 acc2[4][4];
#pragma unroll
        for (int m = 0; m < 4; ++m)
#pragma unroll
            for (int n = 0; n < 4; ++n) acc2[m][n] = 0;
#pragma unroll
        for (int ks = 0; ks < 2; ++ks)
#pragma unroll
            for (int n = 0; n < 4; ++n)
#pragma unroll
                for (int m = 0; m < 4; ++m)
                    acc2[m][n] = __builtin_amdgcn_mfma_f32_16x16x32_bf16(
                        a2[m][ks], b2f[ks][n], acc2[m][n], 0, 0, 0);

#pragma unroll
        for (int n = 0; n < 4; ++n) {
            int col = n * 16 + (lane & 15);
            float bv = b2[col];
            int colch = col >> 3;
#pragma unroll
            for (int m = 0; m < 4; ++m)
#pragma unroll
                for (int r = 0; r < 4; ++r) {
                    int rl = m * 16 + (lane >> 4) * 4 + r;
                    Aw[4096 + rl * 64 + ((colch ^ (rl & 7)) * 8) + (col & 7)] =
                        f2bf(lrelu(acc2[m][n][r] + bv));      // h2 [4096,8192)
                }
        }
    }

    // ---- L3: h3 = lrelu(h2@W3 + b3) -> [64][128] swizzled at [0,8192) ----
    {
        short8 a3[4][2];
#pragma unroll
        for (int m = 0; m < 4; ++m)
#pragma unroll
            for (int ks = 0; ks < 2; ++ks) {
                int rl = m * 16 + (lane & 15);
                int kch = ks * 4 + (lane >> 4);
                a3[m][ks] = *(const short8*)&Aw[4096 + rl * 64 + ((kch ^ (rl & 7)) * 8)];
            }
#pragma unroll
        for (int half = 0; half < 2; ++half) {
            short8 b3f[2][4];
#pragma unroll
            for (int ks = 0; ks < 2; ++ks)
#pragma unroll
                for (int n = 0; n < 4; ++n)
                    b3f[ks][n] = *(const short8*)&F3[(size_t)(half * 8 + ks * 4 + n) * 512 + lane * 8];

            f32x4 acc3[4][4];
#pragma unroll
            for (int m = 0; m < 4; ++m)
#pragma unroll
                for (int n = 0; n < 4; ++n) acc3[m][n] = 0;
#pragma unroll
            for (int ks = 0; ks < 2; ++ks)
#pragma unroll
                for (int n = 0; n < 4; ++n)
#pragma unroll
                    for (int m = 0; m < 4; ++m)
                        acc3[m][n] = __builtin_amdgcn_mfma_f32_16x16x32_bf16(
                            a3[m][ks], b3f[ks][n], acc3[m][n], 0, 0, 0);

#pragma unroll
            for (int n = 0; n < 4; ++n) {
                int col = half * 64 + n * 16 + (lane & 15);
                float bv = b3[col];
                int colch = col >> 3;
#pragma unroll
                for (int m = 0; m < 4; ++m)
#pragma unroll
                    for (int r = 0; r < 4; ++r) {
                        int rl = m * 16 + (lane >> 4) * 4 + r;
                        Aw[rl * 128 + ((colch ^ (rl & 7)) * 8) + (col & 7)] =
                            f2bf(lrelu(acc3[m][n][r] + bv));
                    }
            }
        }
    }

    // ---- extract persistent A-frags ----
    short8 af[4][4];
#pragma unroll
    for (int m = 0; m < 4; ++m)
#pragma unroll
        for (int ks = 0; ks < 4; ++ks) {
            int rl = m * 16 + (lane & 15);
            int ch = (ks * 4 + (lane >> 4)) ^ (rl & 7);
            af[m][ks] = *(const short8*)&Aw[rl * 128 + ch * 8];
        }

    // ---- row mask (block-uniform branch) ----
    const bool full = (sc * 256 + 256) <= len;
    float madd[4][4];
    if (!full) {
#pragma unroll
        for (int m = 0; m < 4; ++m)
#pragma unroll
            for (int r = 0; r < 4; ++r) {
                int rloc = sc * 256 + w * 64 + m * 16 + (lane >> 4) * 4 + r;
                madd[m][r] = (rloc < len) ? 0.0f : -INFINITY;
            }
    }

    // ---- L4: LDS-shared B double buffer (overlays waves 0/1 staging) ----
    // buf[p] = S + p*8192 shorts (16KB each). Wave w stages shorts
    // [w*2048, w*2048+2048) of each buffer: 4 x (short8 load + b128 write).
    short8 stg[4];
#pragma unroll
    for (int i = 0; i < 4; ++i)                  // issue tile-0 loads
        stg[i] = *(const short8*)&F4[w * 2048 + i * 512 + lane * 8];

    __syncthreads();                             // staging reads all done
#pragma unroll
    for (int i = 0; i < 4; ++i)                  // write tile 0 -> buf0
        *(short8*)&S[w * 2048 + i * 512 + lane * 8] = stg[i];

    for (int t = 0; t < 16; ++t) {
        __syncthreads();                         // buf[t&1] published
        if (t < 15) {
#pragma unroll
            for (int i = 0; i < 4; ++i)
                stg[i] = *(const short8*)&F4[(size_t)(t + 1) * 8192 + w * 2048 + i * 512 + lane * 8];
        }

        const short* Bb = S + (t & 1) * 8192;
        f32x4 acc[4][4];
#pragma unroll
        for (int m = 0; m < 4; ++m)
#pragma unroll
            for (int n = 0; n < 4; ++n) acc[m][n] = 0;

#pragma unroll
        for (int ks = 0; ks < 4; ++ks) {
            short8 bfr[4];
#pragma unroll
            for (int n = 0; n < 4; ++n)
                bfr[n] = *(const short8*)&Bb[(ks * 4 + n) * 512 + lane * 8];
#pragma unroll
            for (int n = 0; n < 4; ++n)
#pragma unroll
                for (int m = 0; m < 4; ++m)
                    acc[m][n] = __builtin_amdgcn_mfma_f32_16x16x32_bf16(
                        af[m][ks], bfr[n], acc[m][n], 0, 0, 0);
        }

        // masked max over this wave's 64 rows -> global partials (bf16)
        const size_t pb = ((size_t)((b * 8 + sc) * 4 + w)) * 1024 + t * 64;
#pragma unroll
        for (int n = 0; n < 4; ++n) {
            float v;
            if (full) {
                v = acc[0][n][0];
#pragma unroll
                for (int m = 0; m < 4; ++m)
#pragma unroll
                    for (int r = 0; r < 4; ++r)
                        if (m | r) v = fmaxf(v, acc[m][n][r]);
            } else {
                v = -INFINITY;
#pragma unroll
                for (int m = 0; m < 4; ++m)
#pragma unroll
                    for (int r = 0; r < 4; ++r)
                        v = fmaxf(v, acc[m][n][r] + madd[m][r]);
            }
            v = fmaxf(v, __shfl_xor(v, 16));
            v = fmaxf(v, __shfl_xor(v, 32));
            if (lane < 16) partials[pb + n * 16 + lane] = f2bf(v);
        }

        if (t < 15) {                            // write tile t+1 -> other buf
            short* Bn = S + ((t + 1) & 1) * 8192;
#pragma unroll
            for (int i = 0; i < 4; ++i)
                *(short8*)&Bn[w * 2048 + i * 512 + lane * 8] = stg[i];
        }
    }
}

// ---------------------------------------------------------------------------
// Reduce live superchunk/wave partials (bf16), + b4, LeakyReLU -> pooled bf16.
// ---------------------------------------------------------------------------
__global__ __launch_bounds__(256) void reduce_pool_kernel(
    const short* __restrict__ partials, const int* __restrict__ lengths,
    const float* __restrict__ b4, short* __restrict__ pooled)
{
    const int b = blockIdx.x;
    const int nlive = (lengths[b] + 255) >> 8;   // 1..8
    for (int i = threadIdx.x; i < 1024; i += 256) {
        float m = -INFINITY;
        for (int j = 0; j < nlive; ++j) {
#pragma unroll
            for (int w = 0; w < 4; ++w)
                m = fmaxf(m, bf2f(partials[((size_t)((b * 8 + j) * 4 + w)) * 1024 + i]));
        }
        pooled[(size_t)b * 1024 + i] = f2bf(lrelu(m + b4[i]));
    }
}

// ---------------------------------------------------------------------------
// Tail GEMM on MFMA, 32-col blocks, fully-unrolled K (template) so the
// compiler software-pipelines the weight stream many iterations deep.
// MF=2: M=128 (4 waves x 32 rows), supports fused BN. grid (Nout/32).
// MF=1: M=64 per blockIdx.y (4 waves x 16 rows). grid (Nout/32, 2).
// flags: 1=lrelu, 2=fused BN (bias cancels; MF=2 only), 4=bf16 out.
// ---------------------------------------------------------------------------
template<int MF, int K32>
__global__ __launch_bounds__(256) void gemm_tail(
    const short* __restrict__ A, const short* __restrict__ Wfrag,
    const float* __restrict__ bias,
    const float* __restrict__ g, const float* __restrict__ be,
    float* __restrict__ outF, short* __restrict__ outB,
    int Nout, int flags)
{
    __shared__ float bns[4][32];
    __shared__ float bnq[4][32];

    const int tid = threadIdx.x, lane = tid & 63, w = tid >> 6;
    const int K   = K32 * 32;
    const int c0  = blockIdx.x * 32;
    const int tt  = blockIdx.x >> 1;
    const int hf  = blockIdx.x & 1;
    const int row0  = (MF == 2) ? 0 : blockIdx.y * 64;
    const int arow0 = row0 + w * (MF * 16) + (lane & 15);
    const int koff  = (lane >> 4) * 8;

    f32x4 acc[MF][2];
#pragma unroll
    for (int m = 0; m < MF; ++m) { acc[m][0] = 0; acc[m][1] = 0; }

#pragma unroll
    for (int ks = 0; ks < K32; ++ks) {
        short8 a[MF], bfr[2];
#pragma unroll
        for (int m = 0; m < MF; ++m)
            a[m] = *(const short8*)&A[(size_t)(arow0 + m * 16) * K + ks * 32 + koff];
#pragma unroll
        for (int n = 0; n < 2; ++n)
            bfr[n] = *(const short8*)&Wfrag[(size_t)((tt * K32 + ks) * 4 + hf * 2 + n) * 512 + lane * 8];
#pragma unroll
        for (int n = 0; n < 2; ++n)
#pragma unroll
            for (int m = 0; m < MF; ++m)
                acc[m][n] = __builtin_amdgcn_mfma_f32_16x16x32_bf16(a[m], bfr[n], acc[m][n], 0, 0, 0);
    }

    if ((flags & 2) && MF == 2) {
#pragma unroll
        for (int n = 0; n < 2; ++n) {
            float s = 0.f, q = 0.f;
#pragma unroll
            for (int m = 0; m < MF; ++m)
#pragma unroll
                for (int r = 0; r < 4; ++r) {
                    float v = acc[m][n][r];
                    s += v; q = fmaf(v, v, q);
                }
            s += __shfl_xor(s, 16); s += __shfl_xor(s, 32);
            q += __shfl_xor(q, 16); q += __shfl_xor(q, 32);
            if (lane < 16) { bns[w][n * 16 + lane] = s; bnq[w][n * 16 + lane] = q; }
        }
        __syncthreads();
#pragma unroll
        for (int n = 0; n < 2; ++n) {
            int cl = n * 16 + (lane & 15);
            float s = bns[0][cl] + bns[1][cl] + bns[2][cl] + bns[3][cl];
            float q = bnq[0][cl] + bnq[1][cl] + bnq[2][cl] + bnq[3][cl];
            float mean = s * (1.0f / 128.0f);
            float var  = q * (1.0f / 128.0f) - mean * mean;
            float rs   = 1.0f / sqrtf(var + 1e-5f);
            float gg   = g[c0 + cl] * rs;
            float bb   = be[c0 + cl] - mean * gg;
#pragma unroll
            for (int m = 0; m < MF; ++m)
#pragma unroll
                for (int r = 0; r < 4; ++r)
                    acc[m][n][r] = fmaf(acc[m][n][r], gg, bb);
        }
    } else if (bias) {
#pragma unroll
        for (int n = 0; n < 2; ++n) {
            float bv = bias[c0 + n * 16 + (lane & 15)];
#pragma unroll
            for (int m = 0; m < MF; ++m)
#pragma unroll
                for (int r = 0; r < 4; ++r) acc[m][n][r] += bv;
        }
    }

    if (flags & 1) {
#pragma unroll
        for (int m = 0; m < MF; ++m)
#pragma unroll
            for (int n = 0; n < 2; ++n)
#pragma unroll
                for (int r = 0; r < 4; ++r) acc[m][n][r] = lrelu(acc[m][n][r]);
    }

#pragma unroll
    for (int m = 0; m < MF; ++m)
#pragma unroll
        for (int n = 0; n < 2; ++n)
#pragma unroll
            for (int r = 0; r < 4; ++r) {
                int row = row0 + w * (MF * 16) + m * 16 + (lane >> 4) * 4 + r;
                int col = c0 + n * 16 + (lane & 15);
                if (flags & 4) outB[(size_t)row * Nout + col] = f2bf(acc[m][n][r]);
                else           outF[(size_t)row * Nout + col] = acc[m][n][r];
            }
}

// ---------------------------------------------------------------------------
// mu + logvar + reparameterize, fused. grid (8, 2): 32 cols x 64 rows.
// ---------------------------------------------------------------------------
__global__ __launch_bounds__(256) void gemm_muvlz(
    const short* __restrict__ A, const short* __restrict__ Fmuvl,
    const float* __restrict__ bmu, const float* __restrict__ blv,
    const float* __restrict__ eps,
    float* __restrict__ mu_out, float* __restrict__ lv_out,
    short* __restrict__ zbuf)
{
    const int tid = threadIdx.x, lane = tid & 63, w = tid >> 6;
    const int c0 = blockIdx.x * 32;
    const int tt = blockIdx.x >> 1;
    const int hf = blockIdx.x & 1;
    const int row0 = blockIdx.y * 64;
    const int arow = row0 + w * 16 + (lane & 15);
    const int koff = (lane >> 4) * 8;

    f32x4 macc[2], lacc[2];
#pragma unroll
    for (int n = 0; n < 2; ++n) { macc[n] = 0; lacc[n] = 0; }

#pragma unroll
    for (int ks = 0; ks < 32; ++ks) {
        short8 a = *(const short8*)&A[(size_t)arow * 1024 + ks * 32 + koff];
#pragma unroll
        for (int n = 0; n < 2; ++n) {
            short8 bm = *(const short8*)&Fmuvl[(size_t)((tt * 32 + ks) * 4 + hf * 2 + n) * 512 + lane * 8];
            short8 bl = *(const short8*)&Fmuvl[(size_t)(((tt + 4) * 32 + ks) * 4 + hf * 2 + n) * 512 + lane * 8];
            macc[n] = __builtin_amdgcn_mfma_f32_16x16x32_bf16(a, bm, macc[n], 0, 0, 0);
            lacc[n] = __builtin_amdgcn_mfma_f32_16x16x32_bf16(a, bl, lacc[n], 0, 0, 0);
        }
    }

#pragma unroll
    for (int n = 0; n < 2; ++n) {
        int col = c0 + n * 16 + (lane & 15);
        float bmv = bmu[col], blvv = blv[col];
#pragma unroll
        for (int r = 0; r < 4; ++r) {
            int row = row0 + w * 16 + (lane >> 4) * 4 + r;
            float mu = macc[n][r] + bmv;
            float lv = lacc[n][r] + blvv;
            mu_out[(size_t)row * 256 + col] = mu;
            lv_out[(size_t)row * 256 + col] = lv;
            float z = fmaf(eps[(size_t)row * 256 + col], expf(0.5f * lv), mu);
            zbuf[(size_t)row * 256 + col] = f2bf(z);
        }
    }
}

// ---------------------------------------------------------------------------
extern "C" void kernel_launch(void* const* d_in, const int* in_sizes, int n_in,
                              void* d_out, int out_size, void* d_ws, size_t ws_size,
                              hipStream_t stream)
{
    const float* x       = (const float*)d_in[0];
    const int*   lengths = (const int*)  d_in[1];
    const float* eps     = (const float*)d_in[2];
    const float* W1  = (const float*)d_in[3];  const float* b1  = (const float*)d_in[4];
    const float* W2  = (const float*)d_in[5];  const float* b2  = (const float*)d_in[6];
    const float* W3  = (const float*)d_in[7];  const float* b3  = (const float*)d_in[8];
    const float* W4  = (const float*)d_in[9];  const float* b4  = (const float*)d_in[10];
    const float* Wf  = (const float*)d_in[11]; const float* bf  = (const float*)d_in[12];
    const float* Wmu = (const float*)d_in[13]; const float* bmu = (const float*)d_in[14];
    const float* Wlv = (const float*)d_in[15]; const float* blv = (const float*)d_in[16];
    const float* Wd1 = (const float*)d_in[17];
    const float* g1  = (const float*)d_in[19]; const float* be1 = (const float*)d_in[20];
    const float* Wd2 = (const float*)d_in[21];
    const float* g2  = (const float*)d_in[23]; const float* be2 = (const float*)d_in[24];
    const float* Wd3 = (const float*)d_in[25]; const float* bd3 = (const float*)d_in[26];
    // bd1, bd2 provably cancel inside BatchNorm

    float* out = (float*)d_out;
    float* y_out  = out;               // [128,384]
    float* mu_out = out + 49152;       // [128,256]
    float* lv_out = out + 81920;       // [128,256]

    // ---- workspace layout (bytes) ----
    char* ws = (char*)d_ws;
    short* F4    = (short*)(ws + 0);          // 256 frags * 1KB
    short* Ff    = (short*)(ws + 262144);     // 2048 * 1KB
    short* Fmuvl = (short*)(ws + 2359296);    // 1024 * 1KB
    short* Fd1   = (short*)(ws + 3407872);    // 512 * 1KB
    short* Fd2   = (short*)(ws + 3932160);    // 2048 * 1KB
    short* Fd3   = (short*)(ws + 6029312);    // 768 * 1KB
    short* F2    = (short*)(ws + 6815744);    // 8 * 1KB
    short* F3    = (short*)(ws + 6823936);    // 16 * 1KB
    short* partials = (short*)(ws + 6840320); // 128*8*4*1024 bf16 = 8MB
    short* pooled = (short*)(ws + 15228928);  // 128*1024 bf16
    short* ebuf   = (short*)(ws + 15491072);  // 128*1024
    short* zbuf   = (short*)(ws + 15753216);  // 128*256
    short* d1v    = (short*)(ws + 15818752);  // 128*1024
    short* d2v    = (short*)(ws + 16080896);  // 128*1024

    // 0) pack all MFMA weights
    pack_all<<<1670, 256, 0, stream>>>(W4, Wf, Wmu, Wlv, Wd1, Wd2, Wd3, W2, W3,
                                       F4, Ff, Fmuvl, Fd1, Fd2, Fd3, F2, F3);
    // 1) fused pointnet (4-wave LDS-shared B) + masked max partials
    fused_pointnet_kernel<<<1024, 256, 0, stream>>>(
        x, lengths, W1, b1, b2, b3, F2, F3, F4, partials);
    // 2) finish pool (live superchunks only, +b4, lrelu) -> bf16
    reduce_pool_kernel<<<128, 256, 0, stream>>>(partials, lengths, b4, pooled);
    // 3) e = lrelu(pooled @ Wf + bf) -> bf16
    gemm_tail<1, 32><<<dim3(32, 2), 256, 0, stream>>>(pooled, Ff, bf, nullptr, nullptr,
                                                      nullptr, ebuf, 1024, 1 | 4);
    // 4) mu | logvar | z fused
    gemm_muvlz<<<dim3(8, 2), 256, 0, stream>>>(ebuf, Fmuvl, bmu, blv, eps,
                                               mu_out, lv_out, zbuf);
    // 5) decoder 1: Linear + BN + lrelu -> bf16
    gemm_tail<2, 8><<<32, 256, 0, stream>>>(zbuf, Fd1, nullptr, g1, be1,
                                            nullptr, d1v, 1024, 1 | 2 | 4);
    // 6) decoder 2
    gemm_tail<2, 32><<<32, 256, 0, stream>>>(d1v, Fd2, nullptr, g2, be2,
                                             nullptr, d2v, 1024, 1 | 2 | 4);
    // 7) final linear -> y (fp32)
    gemm_tail<1, 32><<<dim3(12, 2), 256, 0, stream>>>(d2v, Fd3, bd3, nullptr, nullptr,
                                                      y_out, nullptr, 384, 0);
}